// Round 1
// baseline (1971.239 us; speedup 1.0000x reference)
//
#include <hip/hip_runtime.h>
#include <math.h>

// Problem constants
#define NTOK 32768      // B*L = 64*512
#define Hdim 256
#define Ldim 512
#define Bdim 64
#define NHEAD 4
#define HD 64
#define PADV 49999      // ITEMNUM-1

// ---------------- block reduce (256 threads) ----------------
__device__ __forceinline__ float block_reduce_sum(float v, float* sbuf) {
    int lane = threadIdx.x & 63;
    int wid  = threadIdx.x >> 6;
#pragma unroll
    for (int off = 32; off > 0; off >>= 1)
        v += __shfl_down(v, off, 64);
    __syncthreads();            // protect sbuf from previous use
    if (lane == 0) sbuf[wid] = v;
    __syncthreads();
    return sbuf[0] + sbuf[1] + sbuf[2] + sbuf[3];
}

// ---------------- prep: pos-emb add, keep mask, gates ----------------
__global__ __launch_bounds__(256)
void prep_kernel(const int* __restrict__ seqs_data, const float* __restrict__ seqs,
                 const int* __restrict__ position, const float* __restrict__ time_emb,
                 const float* __restrict__ pos_table, const float* __restrict__ gate_W,
                 const float* __restrict__ gate_b,
                 float* __restrict__ S, float* __restrict__ T,
                 float* __restrict__ gates, float* __restrict__ keepv) {
    __shared__ float sbuf[4];
    int tok = blockIdx.x;
    int h   = threadIdx.x;
    int pos = position[tok];
    float pe = pos_table[(size_t)pos * Hdim + h];
    float s  = seqs[(size_t)tok * Hdim + h] + pe;
    float t  = time_emb[(size_t)tok * Hdim + h] + pe;
    float keep = (seqs_data[tok] != PADV) ? 1.0f : 0.0f;
    T[(size_t)tok * Hdim + h] = t;
    S[(size_t)tok * Hdim + h] = s * keep;
    float g0 = t * gate_W[h];
    float g1 = t * gate_W[Hdim + h];
    g0 = block_reduce_sum(g0, sbuf);
    g1 = block_reduce_sum(g1, sbuf);
    if (h == 0) {
        gates[(size_t)tok * 2 + 0] = 1.0f / (1.0f + expf(-(g0 + gate_b[0])));
        gates[(size_t)tok * 2 + 1] = 1.0f / (1.0f + expf(-(g1 + gate_b[1])));
        keepv[tok] = keep;
    }
}

// ---------------- LayerNorm (optionally fused add) ----------------
__global__ __launch_bounds__(256)
void ln_kernel(const float* __restrict__ src, const float* __restrict__ add,
               float* __restrict__ dst, const float* __restrict__ g,
               const float* __restrict__ b) {
    __shared__ float sbuf[4];
    int tok = blockIdx.x;
    int h   = threadIdx.x;
    float x = src[(size_t)tok * Hdim + h];
    if (add) x += add[(size_t)tok * Hdim + h];
    float mean = block_reduce_sum(x, sbuf) * (1.0f / Hdim);
    float d = x - mean;
    float var = block_reduce_sum(d * d, sbuf) * (1.0f / Hdim);
    float r = rsqrtf(var + 1e-8f);
    dst[(size_t)tok * Hdim + h] = d * r * g[h] + b[h];
}

// ---------------- GEMM: C[M,256] = (A(+Aadd)) @ W^T + bias, fused epilogue ----------------
#define BM 64
#define BN 64
#define BK 16
__global__ __launch_bounds__(256)
void gemm_kernel(const float* __restrict__ A, const float* __restrict__ Aadd,
                 const float* __restrict__ W, const float* __restrict__ bias,
                 const float* __restrict__ resid, const float* __restrict__ keepv,
                 float* __restrict__ C, int doRelu) {
    __shared__ float As[BM][BK + 1];
    __shared__ float Ws[BN][BK + 1];
    int n0 = blockIdx.x * BN;
    int m0 = blockIdx.y * BM;
    int tx = threadIdx.x & 15;
    int ty = threadIdx.x >> 4;
    int lr = threadIdx.x >> 2;        // 0..63 tile row
    int lc = (threadIdx.x & 3) * 4;   // 0,4,8,12
    float acc[4][4];
#pragma unroll
    for (int i = 0; i < 4; ++i)
#pragma unroll
        for (int j = 0; j < 4; ++j) acc[i][j] = 0.0f;

    for (int kc = 0; kc < Hdim; kc += BK) {
        float4 av = *(const float4*)(A + (size_t)(m0 + lr) * Hdim + kc + lc);
        if (Aadd) {
            float4 aa = *(const float4*)(Aadd + (size_t)(m0 + lr) * Hdim + kc + lc);
            av.x += aa.x; av.y += aa.y; av.z += aa.z; av.w += aa.w;
        }
        float4 wv = *(const float4*)(W + (size_t)(n0 + lr) * Hdim + kc + lc);
        As[lr][lc + 0] = av.x; As[lr][lc + 1] = av.y;
        As[lr][lc + 2] = av.z; As[lr][lc + 3] = av.w;
        Ws[lr][lc + 0] = wv.x; Ws[lr][lc + 1] = wv.y;
        Ws[lr][lc + 2] = wv.z; Ws[lr][lc + 3] = wv.w;
        __syncthreads();
#pragma unroll
        for (int kk = 0; kk < BK; ++kk) {
            float a[4], w[4];
#pragma unroll
            for (int i = 0; i < 4; ++i) a[i] = As[ty * 4 + i][kk];
#pragma unroll
            for (int j = 0; j < 4; ++j) w[j] = Ws[tx * 4 + j][kk];
#pragma unroll
            for (int i = 0; i < 4; ++i)
#pragma unroll
                for (int j = 0; j < 4; ++j) acc[i][j] += a[i] * w[j];
        }
        __syncthreads();
    }
#pragma unroll
    for (int i = 0; i < 4; ++i) {
        int m = m0 + ty * 4 + i;
        float kf = keepv ? keepv[m] : 1.0f;
#pragma unroll
        for (int j = 0; j < 4; ++j) {
            int n = n0 + tx * 4 + j;
            float c = acc[i][j] + bias[n];
            if (doRelu) c = fmaxf(c, 0.0f);
            if (resid) c += resid[(size_t)m * Hdim + n];
            c *= kf;
            C[(size_t)m * Hdim + n] = c;
        }
    }
}

// ---------------- gated causal flash attention ----------------
// grid: (L/64, NHEAD, B), 256 threads (16x16, 4x4 microtile)
__global__ __launch_bounds__(256)
void attn_kernel(const float* __restrict__ Qb, const float* __restrict__ Kb,
                 const float* __restrict__ Vb, const float* __restrict__ gates,
                 float* __restrict__ Ob, int blk) {
    __shared__ float Qs[64][HD + 1];
    __shared__ float Ks[64][HD + 1];
    __shared__ float Vs[64][HD + 1];
    __shared__ float Ps[64][64 + 1];
    __shared__ float gq[64], gk[64];
    int qt = blockIdx.x;
    int h  = blockIdx.y;
    int b  = blockIdx.z;
    int q0 = qt * 64;
    int tx = threadIdx.x & 15;
    int ty = threadIdx.x >> 4;
    int lr = threadIdx.x >> 2;
    int lc = (threadIdx.x & 3) * 16;
    size_t baseQ = ((size_t)b * Ldim + q0) * Hdim + h * HD;
#pragma unroll
    for (int j = 0; j < 16; j += 4) {
        float4 v = *(const float4*)(Qb + baseQ + (size_t)lr * Hdim + lc + j);
        Qs[lr][lc + j + 0] = v.x; Qs[lr][lc + j + 1] = v.y;
        Qs[lr][lc + j + 2] = v.z; Qs[lr][lc + j + 3] = v.w;
    }
    if (threadIdx.x < 64)
        gq[threadIdx.x] = gates[((size_t)b * Ldim + q0 + threadIdx.x) * 2 + blk];

    float m[4], l[4], accO[4][4];
#pragma unroll
    for (int i = 0; i < 4; ++i) {
        m[i] = -1e30f; l[i] = 0.0f;
#pragma unroll
        for (int j = 0; j < 4; ++j) accO[i][j] = 0.0f;
    }
    const float scale = 0.125f;  // 1/sqrt(64)

    for (int kt = 0; kt <= qt; ++kt) {
        int k0 = kt * 64;
        __syncthreads();   // protect Ks/Vs/Ps/gk from previous iteration readers
        size_t baseK = ((size_t)b * Ldim + k0) * Hdim + h * HD;
#pragma unroll
        for (int j = 0; j < 16; j += 4) {
            float4 kv = *(const float4*)(Kb + baseK + (size_t)lr * Hdim + lc + j);
            Ks[lr][lc + j + 0] = kv.x; Ks[lr][lc + j + 1] = kv.y;
            Ks[lr][lc + j + 2] = kv.z; Ks[lr][lc + j + 3] = kv.w;
            float4 vv = *(const float4*)(Vb + baseK + (size_t)lr * Hdim + lc + j);
            Vs[lr][lc + j + 0] = vv.x; Vs[lr][lc + j + 1] = vv.y;
            Vs[lr][lc + j + 2] = vv.z; Vs[lr][lc + j + 3] = vv.w;
        }
        if (threadIdx.x < 64)
            gk[threadIdx.x] = gates[((size_t)b * Ldim + k0 + threadIdx.x) * 2 + blk];
        __syncthreads();

        // scores 4x4 microtile
        float s[4][4];
#pragma unroll
        for (int i = 0; i < 4; ++i)
#pragma unroll
            for (int j = 0; j < 4; ++j) s[i][j] = 0.0f;
        for (int d = 0; d < HD; ++d) {
            float qv[4], kv[4];
#pragma unroll
            for (int i = 0; i < 4; ++i) qv[i] = Qs[ty * 4 + i][d];
#pragma unroll
            for (int j = 0; j < 4; ++j) kv[j] = Ks[tx * 4 + j][d];
#pragma unroll
            for (int i = 0; i < 4; ++i)
#pragma unroll
                for (int j = 0; j < 4; ++j) s[i][j] += qv[i] * kv[j];
        }
        bool diag = (kt == qt);
#pragma unroll
        for (int i = 0; i < 4; ++i) {
            float gqi = gq[ty * 4 + i] * scale;
#pragma unroll
            for (int j = 0; j < 4; ++j) {
                float val = s[i][j] * gqi * gk[tx * 4 + j];
                if (diag && (tx * 4 + j > ty * 4 + i)) val = -1e30f;
                s[i][j] = val;
            }
        }
        // online softmax update (rows owned by 16 tx-lanes, reduce over width 16)
#pragma unroll
        for (int i = 0; i < 4; ++i) {
            float mx = fmaxf(fmaxf(s[i][0], s[i][1]), fmaxf(s[i][2], s[i][3]));
#pragma unroll
            for (int off = 1; off < 16; off <<= 1)
                mx = fmaxf(mx, __shfl_xor(mx, off, 16));
            float mnew = fmaxf(m[i], mx);
            float alpha = expf(m[i] - mnew);
            float su = 0.0f;
#pragma unroll
            for (int j = 0; j < 4; ++j) {
                float p = expf(s[i][j] - mnew);
                s[i][j] = p;
                su += p;
            }
#pragma unroll
            for (int off = 1; off < 16; off <<= 1)
                su += __shfl_xor(su, off, 16);
            l[i] = l[i] * alpha + su;
            m[i] = mnew;
#pragma unroll
            for (int j = 0; j < 4; ++j) accO[i][j] *= alpha;
        }
#pragma unroll
        for (int i = 0; i < 4; ++i)
#pragma unroll
            for (int j = 0; j < 4; ++j) Ps[ty * 4 + i][tx * 4 + j] = s[i][j];
        __syncthreads();
        // O += P @ V
        for (int kc = 0; kc < 64; ++kc) {
            float pv[4], vv[4];
#pragma unroll
            for (int i = 0; i < 4; ++i) pv[i] = Ps[ty * 4 + i][kc];
#pragma unroll
            for (int j = 0; j < 4; ++j) vv[j] = Vs[kc][tx * 4 + j];
#pragma unroll
            for (int i = 0; i < 4; ++i)
#pragma unroll
                for (int j = 0; j < 4; ++j) accO[i][j] += pv[i] * vv[j];
        }
    }
#pragma unroll
    for (int i = 0; i < 4; ++i) {
        float inv = 1.0f / l[i];
#pragma unroll
        for (int j = 0; j < 4; ++j)
            Ob[baseQ + (size_t)(ty * 4 + i) * Hdim + tx * 4 + j] = accO[i][j] * inv;
    }
}

// ---------------- launcher ----------------
extern "C" void kernel_launch(void* const* d_in, const int* in_sizes, int n_in,
                              void* d_out, int out_size, void* d_ws, size_t ws_size,
                              hipStream_t stream) {
    const int*   seqs_data = (const int*)d_in[0];
    const float* seqs      = (const float*)d_in[1];
    const int*   position  = (const int*)d_in[2];
    const float* time_emb  = (const float*)d_in[3];
    const float* pos_table = (const float*)d_in[4];
    const float* gate_W    = (const float*)d_in[5];
    const float* gate_b    = (const float*)d_in[6];
    const float* ln_attn_g = (const float*)d_in[7];
    const float* ln_attn_b = (const float*)d_in[8];
    const float* qW        = (const float*)d_in[9];
    const float* qb        = (const float*)d_in[10];
    const float* kW        = (const float*)d_in[11];
    const float* kb        = (const float*)d_in[12];
    const float* vW        = (const float*)d_in[13];
    const float* vb        = (const float*)d_in[14];
    const float* ln_ffn_g  = (const float*)d_in[15];
    const float* ln_ffn_b  = (const float*)d_in[16];
    const float* c1W       = (const float*)d_in[17];
    const float* c1b       = (const float*)d_in[18];
    const float* c2W       = (const float*)d_in[19];
    const float* c2b       = (const float*)d_in[20];
    const float* last_g    = (const float*)d_in[21];
    const float* last_b    = (const float*)d_in[22];

    float* S  = (float*)d_out;          // evolving seqs lives in d_out
    float* ws = (float*)d_ws;
    size_t BUF = (size_t)NTOK * Hdim;
    float* T     = ws;                  // time (constant over blocks)
    float* QX    = T + BUF;             // LN output Q, later X
    float* QA    = QX + BUF;            // q, then attn out
    float* KB    = QA + BUF;            // k, then ffn hidden
    float* VB    = KB + BUF;            // v
    float* GATES = VB + BUF;            // NTOK*2
    float* KEEP  = GATES + (size_t)NTOK * 2;  // NTOK

    prep_kernel<<<NTOK, 256, 0, stream>>>(seqs_data, seqs, position, time_emb,
                                          pos_table, gate_W, gate_b,
                                          S, T, GATES, KEEP);

    dim3 ggrid(Hdim / BN, NTOK / BM);
    dim3 agrid(Ldim / 64, NHEAD, Bdim);
    for (int i = 0; i < 2; ++i) {
        const float* qWi = qW + (size_t)i * Hdim * Hdim;
        const float* kWi = kW + (size_t)i * Hdim * Hdim;
        const float* vWi = vW + (size_t)i * Hdim * Hdim;
        const float* c1Wi = c1W + (size_t)i * Hdim * Hdim;
        const float* c2Wi = c2W + (size_t)i * Hdim * Hdim;

        ln_kernel<<<NTOK, 256, 0, stream>>>(S, nullptr, QX,
                                            ln_attn_g + i * Hdim, ln_attn_b + i * Hdim);
        gemm_kernel<<<ggrid, 256, 0, stream>>>(QX, nullptr, qWi, qb + i * Hdim,
                                               nullptr, nullptr, QA, 0);
        gemm_kernel<<<ggrid, 256, 0, stream>>>(T, nullptr, kWi, kb + i * Hdim,
                                               nullptr, nullptr, KB, 0);
        gemm_kernel<<<ggrid, 256, 0, stream>>>(S, T, vWi, vb + i * Hdim,
                                               nullptr, nullptr, VB, 0);
        attn_kernel<<<agrid, 256, 0, stream>>>(QA, KB, VB, GATES, QA, i);
        ln_kernel<<<NTOK, 256, 0, stream>>>(QX, QA, QX,
                                            ln_ffn_g + i * Hdim, ln_ffn_b + i * Hdim);
        gemm_kernel<<<ggrid, 256, 0, stream>>>(QX, nullptr, c1Wi, c1b + i * Hdim,
                                               nullptr, nullptr, KB, 1);
        gemm_kernel<<<ggrid, 256, 0, stream>>>(KB, nullptr, c2Wi, c2b + i * Hdim,
                                               QX, KEEP, S, 0);
    }
    ln_kernel<<<NTOK, 256, 0, stream>>>(S, nullptr, S, last_g, last_b);
}

// Round 2
// 1284.539 us; speedup vs baseline: 1.5346x; 1.5346x over previous
//
#include <hip/hip_runtime.h>
#include <hip/hip_bf16.h>
#include <math.h>

// Problem constants
#define NTOK 32768      // B*L = 64*512
#define Hdim 256
#define Ldim 512
#define Bdim 64
#define NHEAD 4
#define HD 64
#define PADV 49999      // ITEMNUM-1

typedef __bf16 bf16x8 __attribute__((ext_vector_type(8)));
typedef float  f32x4  __attribute__((ext_vector_type(4)));

// float -> bf16 (RNE) bit pattern
__device__ __forceinline__ unsigned short f2bf(float f) {
    unsigned int u = __float_as_uint(f);
    unsigned int r = (u + 0x7fffu + ((u >> 16) & 1u)) >> 16;
    return (unsigned short)r;
}

// async global->LDS, 16B per lane (dest must be wave-uniform base + lane*16)
__device__ __forceinline__ void gload16(const void* g, void* l) {
    __builtin_amdgcn_global_load_lds((const __attribute__((address_space(1))) unsigned int*)g,
                                     (__attribute__((address_space(3))) unsigned int*)l,
                                     16, 0, 0);
}

// ---------------- block reduce (256 threads) ----------------
__device__ __forceinline__ float block_reduce_sum(float v, float* sbuf) {
    int lane = threadIdx.x & 63;
    int wid  = threadIdx.x >> 6;
#pragma unroll
    for (int off = 32; off > 0; off >>= 1)
        v += __shfl_down(v, off, 64);
    __syncthreads();
    if (lane == 0) sbuf[wid] = v;
    __syncthreads();
    return sbuf[0] + sbuf[1] + sbuf[2] + sbuf[3];
}

// ---------------- weight cast: 5 matrices x (2*256*256) f32 -> bf16 ----------------
__global__ __launch_bounds__(256)
void castw_kernel(const float* __restrict__ q, const float* __restrict__ k,
                  const float* __restrict__ v, const float* __restrict__ c1,
                  const float* __restrict__ c2, unsigned short* __restrict__ dst) {
    const float* srcs[5] = {q, k, v, c1, c2};
    const float* s = srcs[blockIdx.y];
    int idx = blockIdx.x * 1024 + threadIdx.x * 4;
    float4 f = *(const float4*)(s + idx);
    unsigned short* d = dst + (size_t)blockIdx.y * 131072 + idx;
    d[0] = f2bf(f.x); d[1] = f2bf(f.y); d[2] = f2bf(f.z); d[3] = f2bf(f.w);
}

// ---------------- prep: pos-emb add, keep mask, gates, bf16(T) ----------------
__global__ __launch_bounds__(256)
void prep_kernel(const int* __restrict__ seqs_data, const float* __restrict__ seqs,
                 const int* __restrict__ position, const float* __restrict__ time_emb,
                 const float* __restrict__ pos_table, const float* __restrict__ gate_W,
                 const float* __restrict__ gate_b,
                 float* __restrict__ S, float* __restrict__ T,
                 unsigned short* __restrict__ Tbf,
                 float* __restrict__ gates, float* __restrict__ keepv) {
    __shared__ float sbuf[4];
    int tok = blockIdx.x;
    int h   = threadIdx.x;
    int pos = position[tok];
    float pe = pos_table[(size_t)pos * Hdim + h];
    float s  = seqs[(size_t)tok * Hdim + h] + pe;
    float t  = time_emb[(size_t)tok * Hdim + h] + pe;
    float keep = (seqs_data[tok] != PADV) ? 1.0f : 0.0f;
    T[(size_t)tok * Hdim + h]   = t;
    Tbf[(size_t)tok * Hdim + h] = f2bf(t);
    S[(size_t)tok * Hdim + h]   = s * keep;
    float g0 = t * gate_W[h];
    float g1 = t * gate_W[Hdim + h];
    g0 = block_reduce_sum(g0, sbuf);
    g1 = block_reduce_sum(g1, sbuf);
    if (h == 0) {
        gates[(size_t)tok * 2 + 0] = 1.0f / (1.0f + expf(-(g0 + gate_b[0])));
        gates[(size_t)tok * 2 + 1] = 1.0f / (1.0f + expf(-(g1 + gate_b[1])));
        keepv[tok] = keep;
    }
}

// ---------------- LayerNorm (+optional add, bf16 out, bf16(x+T) vin out) ----------------
__global__ __launch_bounds__(256)
void ln_kernel(const float* __restrict__ src, const float* __restrict__ add,
               const float* __restrict__ Tvin,
               float* __restrict__ dstF, unsigned short* __restrict__ dstBF,
               unsigned short* __restrict__ vinBF,
               const float* __restrict__ g, const float* __restrict__ b) {
    __shared__ float sbuf[4];
    int tok = blockIdx.x;
    int h   = threadIdx.x;
    size_t off = (size_t)tok * Hdim + h;
    float x = src[off];
    if (add) x += add[off];
    if (vinBF) vinBF[off] = f2bf(x + Tvin[off]);
    float mean = block_reduce_sum(x, sbuf) * (1.0f / Hdim);
    float d = x - mean;
    float var = block_reduce_sum(d * d, sbuf) * (1.0f / Hdim);
    float r = rsqrtf(var + 1e-8f);
    float y = d * r * g[h] + b[h];
    if (dstF)  dstF[off]  = y;
    if (dstBF) dstBF[off] = f2bf(y);
}

// ---------------- bf16 MFMA GEMM: C[M,256] = A @ W^T + bias (m97 structure) ----------------
// A: M x 256 bf16 row-major; W: 256 x 256 bf16 row-major (i.e. B^T, K-contiguous)
// block tile 128x128, 4 waves in 2x2, each wave 4x4 MFMA 16x16x32 tiles
#define GBM 128
#define GBN 128
#define GBK 32
__global__ __launch_bounds__(256)
void gemm_bf16_kernel(const unsigned short* __restrict__ A,
                      const unsigned short* __restrict__ W,
                      const float* __restrict__ bias,
                      const float* __restrict__ resid,
                      const float* __restrict__ keepv,
                      float* __restrict__ outF,
                      unsigned short* __restrict__ outBF,
                      int doRelu) {
    __shared__ __bf16 As[GBM][GBK];   // 8 KB
    __shared__ __bf16 Ws[GBN][GBK];   // 8 KB
    int tid  = threadIdx.x;
    int lane = tid & 63;
    int w    = tid >> 6;
    int wr   = w >> 1, wc = w & 1;
    int m0 = blockIdx.y * GBM;
    int n0 = blockIdx.x * GBN;

    f32x4 acc[4][4];
#pragma unroll
    for (int i = 0; i < 4; ++i)
#pragma unroll
        for (int j = 0; j < 4; ++j) acc[i][j] = (f32x4)(0.0f);

    // staging chunk mapping: chunk c (16B) -> row c>>2, col8 (c&3)*8
    int cA = tid, cB = tid + 256;
    int rA = cA >> 2, kA = (cA & 3) * 8;
    int rB = cB >> 2, kB = (cB & 3) * 8;
    int mrow = lane & 15;
    int kq   = (lane >> 4) * 8;

    for (int kc = 0; kc < Hdim; kc += GBK) {
        __syncthreads();
        gload16(A + (size_t)(m0 + rA) * Hdim + kc + kA, (__bf16*)As + cA * 8);
        gload16(A + (size_t)(m0 + rB) * Hdim + kc + kB, (__bf16*)As + cB * 8);
        gload16(W + (size_t)(n0 + rA) * Hdim + kc + kA, (__bf16*)Ws + cA * 8);
        gload16(W + (size_t)(n0 + rB) * Hdim + kc + kB, (__bf16*)Ws + cB * 8);
        __syncthreads();
        bf16x8 af[4], bf[4];
#pragma unroll
        for (int i = 0; i < 4; ++i)
            af[i] = *(const bf16x8*)&As[wr * 64 + i * 16 + mrow][kq];
#pragma unroll
        for (int j = 0; j < 4; ++j)
            bf[j] = *(const bf16x8*)&Ws[wc * 64 + j * 16 + mrow][kq];
#pragma unroll
        for (int i = 0; i < 4; ++i)
#pragma unroll
            for (int j = 0; j < 4; ++j)
                acc[i][j] = __builtin_amdgcn_mfma_f32_16x16x32_bf16(af[i], bf[j], acc[i][j], 0, 0, 0);
    }

    // epilogue: C/D layout col=lane&15, row=(lane>>4)*4+reg
    int colq = lane & 15;
    int rowq = (lane >> 4) * 4;
#pragma unroll
    for (int i = 0; i < 4; ++i) {
#pragma unroll
        for (int r = 0; r < 4; ++r) {
            int m = m0 + wr * 64 + i * 16 + rowq + r;
            float kf = keepv ? keepv[m] : 1.0f;
#pragma unroll
            for (int j = 0; j < 4; ++j) {
                int n = n0 + wc * 64 + j * 16 + colq;
                float v = acc[i][j][r] + bias[n];
                if (doRelu) v = fmaxf(v, 0.0f);
                if (resid) v += resid[(size_t)m * Hdim + n];
                v *= kf;
                if (outF)  outF[(size_t)m * Hdim + n]  = v;
                if (outBF) outBF[(size_t)m * Hdim + n] = f2bf(v);
            }
        }
    }
}

// ---------------- gated causal flash attention (f32, unchanged) ----------------
__global__ __launch_bounds__(256)
void attn_kernel(const float* __restrict__ Qb, const float* __restrict__ Kb,
                 const float* __restrict__ Vb, const float* __restrict__ gates,
                 float* __restrict__ Ob, int blk) {
    __shared__ float Qs[64][HD + 1];
    __shared__ float Ks[64][HD + 1];
    __shared__ float Vs[64][HD + 1];
    __shared__ float Ps[64][64 + 1];
    __shared__ float gq[64], gk[64];
    int qt = blockIdx.x;
    int h  = blockIdx.y;
    int b  = blockIdx.z;
    int q0 = qt * 64;
    int tx = threadIdx.x & 15;
    int ty = threadIdx.x >> 4;
    int lr = threadIdx.x >> 2;
    int lc = (threadIdx.x & 3) * 16;
    size_t baseQ = ((size_t)b * Ldim + q0) * Hdim + h * HD;
#pragma unroll
    for (int j = 0; j < 16; j += 4) {
        float4 v = *(const float4*)(Qb + baseQ + (size_t)lr * Hdim + lc + j);
        Qs[lr][lc + j + 0] = v.x; Qs[lr][lc + j + 1] = v.y;
        Qs[lr][lc + j + 2] = v.z; Qs[lr][lc + j + 3] = v.w;
    }
    if (threadIdx.x < 64)
        gq[threadIdx.x] = gates[((size_t)b * Ldim + q0 + threadIdx.x) * 2 + blk];

    float m[4], l[4], accO[4][4];
#pragma unroll
    for (int i = 0; i < 4; ++i) {
        m[i] = -1e30f; l[i] = 0.0f;
#pragma unroll
        for (int j = 0; j < 4; ++j) accO[i][j] = 0.0f;
    }
    const float scale = 0.125f;  // 1/sqrt(64)

    for (int kt = 0; kt <= qt; ++kt) {
        int k0 = kt * 64;
        __syncthreads();
        size_t baseK = ((size_t)b * Ldim + k0) * Hdim + h * HD;
#pragma unroll
        for (int j = 0; j < 16; j += 4) {
            float4 kv = *(const float4*)(Kb + baseK + (size_t)lr * Hdim + lc + j);
            Ks[lr][lc + j + 0] = kv.x; Ks[lr][lc + j + 1] = kv.y;
            Ks[lr][lc + j + 2] = kv.z; Ks[lr][lc + j + 3] = kv.w;
            float4 vv = *(const float4*)(Vb + baseK + (size_t)lr * Hdim + lc + j);
            Vs[lr][lc + j + 0] = vv.x; Vs[lr][lc + j + 1] = vv.y;
            Vs[lr][lc + j + 2] = vv.z; Vs[lr][lc + j + 3] = vv.w;
        }
        if (threadIdx.x < 64)
            gk[threadIdx.x] = gates[((size_t)b * Ldim + k0 + threadIdx.x) * 2 + blk];
        __syncthreads();

        float s[4][4];
#pragma unroll
        for (int i = 0; i < 4; ++i)
#pragma unroll
            for (int j = 0; j < 4; ++j) s[i][j] = 0.0f;
        for (int d = 0; d < HD; ++d) {
            float qv[4], kv[4];
#pragma unroll
            for (int i = 0; i < 4; ++i) qv[i] = Qs[ty * 4 + i][d];
#pragma unroll
            for (int j = 0; j < 4; ++j) kv[j] = Ks[tx * 4 + j][d];
#pragma unroll
            for (int i = 0; i < 4; ++i)
#pragma unroll
                for (int j = 0; j < 4; ++j) s[i][j] += qv[i] * kv[j];
        }
        bool diag = (kt == qt);
#pragma unroll
        for (int i = 0; i < 4; ++i) {
            float gqi = gq[ty * 4 + i] * scale;
#pragma unroll
            for (int j = 0; j < 4; ++j) {
                float val = s[i][j] * gqi * gk[tx * 4 + j];
                if (diag && (tx * 4 + j > ty * 4 + i)) val = -1e30f;
                s[i][j] = val;
            }
        }
#pragma unroll
        for (int i = 0; i < 4; ++i) {
            float mx = fmaxf(fmaxf(s[i][0], s[i][1]), fmaxf(s[i][2], s[i][3]));
#pragma unroll
            for (int off = 1; off < 16; off <<= 1)
                mx = fmaxf(mx, __shfl_xor(mx, off, 16));
            float mnew = fmaxf(m[i], mx);
            float alpha = expf(m[i] - mnew);
            float su = 0.0f;
#pragma unroll
            for (int j = 0; j < 4; ++j) {
                float p = expf(s[i][j] - mnew);
                s[i][j] = p;
                su += p;
            }
#pragma unroll
            for (int off = 1; off < 16; off <<= 1)
                su += __shfl_xor(su, off, 16);
            l[i] = l[i] * alpha + su;
            m[i] = mnew;
#pragma unroll
            for (int j = 0; j < 4; ++j) accO[i][j] *= alpha;
        }
#pragma unroll
        for (int i = 0; i < 4; ++i)
#pragma unroll
            for (int j = 0; j < 4; ++j) Ps[ty * 4 + i][tx * 4 + j] = s[i][j];
        __syncthreads();
        for (int kc = 0; kc < 64; ++kc) {
            float pv[4], vv[4];
#pragma unroll
            for (int i = 0; i < 4; ++i) pv[i] = Ps[ty * 4 + i][kc];
#pragma unroll
            for (int j = 0; j < 4; ++j) vv[j] = Vs[kc][tx * 4 + j];
#pragma unroll
            for (int i = 0; i < 4; ++i)
#pragma unroll
                for (int j = 0; j < 4; ++j) accO[i][j] += pv[i] * vv[j];
        }
    }
#pragma unroll
    for (int i = 0; i < 4; ++i) {
        float inv = 1.0f / l[i];
#pragma unroll
        for (int j = 0; j < 4; ++j)
            Ob[baseQ + (size_t)(ty * 4 + i) * Hdim + tx * 4 + j] = accO[i][j] * inv;
    }
}

// ---------------- launcher ----------------
extern "C" void kernel_launch(void* const* d_in, const int* in_sizes, int n_in,
                              void* d_out, int out_size, void* d_ws, size_t ws_size,
                              hipStream_t stream) {
    const int*   seqs_data = (const int*)d_in[0];
    const float* seqs      = (const float*)d_in[1];
    const int*   position  = (const int*)d_in[2];
    const float* time_emb  = (const float*)d_in[3];
    const float* pos_table = (const float*)d_in[4];
    const float* gate_W    = (const float*)d_in[5];
    const float* gate_b    = (const float*)d_in[6];
    const float* ln_attn_g = (const float*)d_in[7];
    const float* ln_attn_b = (const float*)d_in[8];
    const float* qW        = (const float*)d_in[9];
    const float* qb        = (const float*)d_in[10];
    const float* kW        = (const float*)d_in[11];
    const float* kb        = (const float*)d_in[12];
    const float* vW        = (const float*)d_in[13];
    const float* vb        = (const float*)d_in[14];
    const float* ln_ffn_g  = (const float*)d_in[15];
    const float* ln_ffn_b  = (const float*)d_in[16];
    const float* c1W       = (const float*)d_in[17];
    const float* c1b       = (const float*)d_in[18];
    const float* c2W       = (const float*)d_in[19];
    const float* c2b       = (const float*)d_in[20];
    const float* last_g    = (const float*)d_in[21];
    const float* last_b    = (const float*)d_in[22];

    float* S = (float*)d_out;           // evolving seqs in d_out
    size_t BUF = (size_t)NTOK * Hdim;
    float* fws = (float*)d_ws;
    float* T   = fws;                   // time f32 (constant over blocks)
    float* QX  = T + BUF;               // LN out f32 / residual x
    float* QA  = QX + BUF;              // q, then attn out (f32)
    float* KB  = QA + BUF;              // k (f32)
    float* VB  = KB + BUF;              // v (f32)
    float* GATES = VB + BUF;            // NTOK*2
    float* KEEP  = GATES + (size_t)NTOK * 2;
    unsigned short* bws   = (unsigned short*)(KEEP + NTOK);
    unsigned short* Tbf   = bws;            // bf16(T)
    unsigned short* QXbf  = Tbf + BUF;      // bf16(LN out)
    unsigned short* VINbf = QXbf + BUF;     // bf16(S+T), reused as bf16 hidden
    unsigned short* Wbf   = VINbf + BUF;    // 10 x 65536 bf16 weights
    size_t WB = (size_t)Hdim * Hdim;        // 65536 per matrix
    unsigned short* qWbf  = Wbf;
    unsigned short* kWbf  = Wbf + 2 * WB;
    unsigned short* vWbf  = Wbf + 4 * WB;
    unsigned short* c1Wbf = Wbf + 6 * WB;
    unsigned short* c2Wbf = Wbf + 8 * WB;

    castw_kernel<<<dim3(128, 5), 256, 0, stream>>>(qW, kW, vW, c1W, c2W, Wbf);
    prep_kernel<<<NTOK, 256, 0, stream>>>(seqs_data, seqs, position, time_emb,
                                          pos_table, gate_W, gate_b,
                                          S, T, Tbf, GATES, KEEP);

    dim3 ggrid(Hdim / GBN, NTOK / GBM);   // (2, 256)
    dim3 agrid(Ldim / 64, NHEAD, Bdim);
    for (int i = 0; i < 2; ++i) {
        ln_kernel<<<NTOK, 256, 0, stream>>>(S, nullptr, T, QX, QXbf, VINbf,
                                            ln_attn_g + i * Hdim, ln_attn_b + i * Hdim);
        gemm_bf16_kernel<<<ggrid, 256, 0, stream>>>(QXbf, qWbf + i * WB, qb + i * Hdim,
                                                    nullptr, nullptr, QA, nullptr, 0);
        gemm_bf16_kernel<<<ggrid, 256, 0, stream>>>(Tbf, kWbf + i * WB, kb + i * Hdim,
                                                    nullptr, nullptr, KB, nullptr, 0);
        gemm_bf16_kernel<<<ggrid, 256, 0, stream>>>(VINbf, vWbf + i * WB, vb + i * Hdim,
                                                    nullptr, nullptr, VB, nullptr, 0);
        attn_kernel<<<agrid, 256, 0, stream>>>(QA, KB, VB, GATES, QA, i);
        ln_kernel<<<NTOK, 256, 0, stream>>>(QX, QA, nullptr, QX, QXbf, nullptr,
                                            ln_ffn_g + i * Hdim, ln_ffn_b + i * Hdim);
        // c1: hidden -> bf16 only (input to c2)
        gemm_bf16_kernel<<<ggrid, 256, 0, stream>>>(QXbf, c1Wbf + i * WB, c1b + i * Hdim,
                                                    nullptr, nullptr, nullptr, VINbf, 1);
        // c2: + resid(QX), * keep -> S f32
        gemm_bf16_kernel<<<ggrid, 256, 0, stream>>>(VINbf, c2Wbf + i * WB, c2b + i * Hdim,
                                                    QX, KEEP, S, nullptr, 0);
    }
    ln_kernel<<<NTOK, 256, 0, stream>>>(S, nullptr, nullptr, S, nullptr, nullptr,
                                        last_g, last_b);
}

// Round 3
// 665.982 us; speedup vs baseline: 2.9599x; 1.9288x over previous
//
#include <hip/hip_runtime.h>
#include <hip/hip_bf16.h>
#include <math.h>

// Problem constants
#define NTOK 32768      // B*L = 64*512
#define Hdim 256
#define Ldim 512
#define Bdim 64
#define NHEAD 4
#define HD 64
#define PADV 49999      // ITEMNUM-1

typedef __bf16 bf16x8 __attribute__((ext_vector_type(8)));
typedef float  f32x4  __attribute__((ext_vector_type(4)));

// float -> bf16 (RNE) bit pattern
__device__ __forceinline__ unsigned short f2bf(float f) {
    unsigned int u = __float_as_uint(f);
    unsigned int r = (u + 0x7fffu + ((u >> 16) & 1u)) >> 16;
    return (unsigned short)r;
}

// async global->LDS, 16B per lane (dest must be wave-uniform base + lane*16)
__device__ __forceinline__ void gload16(const void* g, void* l) {
    __builtin_amdgcn_global_load_lds((const __attribute__((address_space(1))) unsigned int*)g,
                                     (__attribute__((address_space(3))) unsigned int*)l,
                                     16, 0, 0);
}

// ---------------- block reduce (256 threads) ----------------
__device__ __forceinline__ float block_reduce_sum(float v, float* sbuf) {
    int lane = threadIdx.x & 63;
    int wid  = threadIdx.x >> 6;
#pragma unroll
    for (int off = 32; off > 0; off >>= 1)
        v += __shfl_down(v, off, 64);
    __syncthreads();
    if (lane == 0) sbuf[wid] = v;
    __syncthreads();
    return sbuf[0] + sbuf[1] + sbuf[2] + sbuf[3];
}

// ---------------- weight cast: 5 matrices x (2*256*256) f32 -> bf16 ----------------
__global__ __launch_bounds__(256)
void castw_kernel(const float* __restrict__ q, const float* __restrict__ k,
                  const float* __restrict__ v, const float* __restrict__ c1,
                  const float* __restrict__ c2, unsigned short* __restrict__ dst) {
    const float* srcs[5] = {q, k, v, c1, c2};
    const float* s = srcs[blockIdx.y];
    int idx = blockIdx.x * 1024 + threadIdx.x * 4;
    float4 f = *(const float4*)(s + idx);
    unsigned short* d = dst + (size_t)blockIdx.y * 131072 + idx;
    d[0] = f2bf(f.x); d[1] = f2bf(f.y); d[2] = f2bf(f.z); d[3] = f2bf(f.w);
}

// ---------------- prep: pos-emb add, keep mask, gates, bf16(T) ----------------
__global__ __launch_bounds__(256)
void prep_kernel(const int* __restrict__ seqs_data, const float* __restrict__ seqs,
                 const int* __restrict__ position, const float* __restrict__ time_emb,
                 const float* __restrict__ pos_table, const float* __restrict__ gate_W,
                 const float* __restrict__ gate_b,
                 float* __restrict__ S, float* __restrict__ T,
                 unsigned short* __restrict__ Tbf,
                 float* __restrict__ gates, float* __restrict__ keepv) {
    __shared__ float sbuf[4];
    int tok = blockIdx.x;
    int h   = threadIdx.x;
    int pos = position[tok];
    float pe = pos_table[(size_t)pos * Hdim + h];
    float s  = seqs[(size_t)tok * Hdim + h] + pe;
    float t  = time_emb[(size_t)tok * Hdim + h] + pe;
    float keep = (seqs_data[tok] != PADV) ? 1.0f : 0.0f;
    T[(size_t)tok * Hdim + h]   = t;
    Tbf[(size_t)tok * Hdim + h] = f2bf(t);
    S[(size_t)tok * Hdim + h]   = s * keep;
    float g0 = t * gate_W[h];
    float g1 = t * gate_W[Hdim + h];
    g0 = block_reduce_sum(g0, sbuf);
    g1 = block_reduce_sum(g1, sbuf);
    if (h == 0) {
        gates[(size_t)tok * 2 + 0] = 1.0f / (1.0f + expf(-(g0 + gate_b[0])));
        gates[(size_t)tok * 2 + 1] = 1.0f / (1.0f + expf(-(g1 + gate_b[1])));
        keepv[tok] = keep;
    }
}

// ---------------- LayerNorm (+optional add, bf16 out, bf16(x+T) vin out) ----------------
__global__ __launch_bounds__(256)
void ln_kernel(const float* __restrict__ src, const float* __restrict__ add,
               const float* __restrict__ Tvin,
               float* __restrict__ dstF, unsigned short* __restrict__ dstBF,
               unsigned short* __restrict__ vinBF,
               const float* __restrict__ g, const float* __restrict__ b) {
    __shared__ float sbuf[4];
    int tok = blockIdx.x;
    int h   = threadIdx.x;
    size_t off = (size_t)tok * Hdim + h;
    float x = src[off];
    if (add) x += add[off];
    if (vinBF) vinBF[off] = f2bf(x + Tvin[off]);
    float mean = block_reduce_sum(x, sbuf) * (1.0f / Hdim);
    float d = x - mean;
    float var = block_reduce_sum(d * d, sbuf) * (1.0f / Hdim);
    float r = rsqrtf(var + 1e-8f);
    float y = d * r * g[h] + b[h];
    if (dstF)  dstF[off]  = y;
    if (dstBF) dstBF[off] = f2bf(y);
}

// ---------------- bf16 MFMA GEMM: C[M,256] = A @ W^T + bias (m97 structure) ----------------
// A: M x 256 bf16 row-major; W: 256 x 256 bf16 row-major (B^T, K-contiguous)
// block tile 128x128, 4 waves 2x2, each wave 4x4 MFMA 16x16x32 tiles
// outVT: write bf16 transposed V layout [B][NH][HD][L]
#define GBM 128
#define GBN 128
#define GBK 32
__global__ __launch_bounds__(256)
void gemm_bf16_kernel(const unsigned short* __restrict__ A,
                      const unsigned short* __restrict__ W,
                      const float* __restrict__ bias,
                      const float* __restrict__ resid,
                      const float* __restrict__ keepv,
                      float* __restrict__ outF,
                      unsigned short* __restrict__ outBF,
                      unsigned short* __restrict__ outVT,
                      int doRelu) {
    __shared__ __bf16 As[GBM][GBK];   // 8 KB
    __shared__ __bf16 Ws[GBN][GBK];   // 8 KB
    int tid  = threadIdx.x;
    int lane = tid & 63;
    int w    = tid >> 6;
    int wr   = w >> 1, wc = w & 1;
    int m0 = blockIdx.y * GBM;
    int n0 = blockIdx.x * GBN;

    f32x4 acc[4][4];
#pragma unroll
    for (int i = 0; i < 4; ++i)
#pragma unroll
        for (int j = 0; j < 4; ++j) acc[i][j] = (f32x4)(0.0f);

    int cA = tid, cB = tid + 256;
    int rA = cA >> 2, kA = (cA & 3) * 8;
    int rB = cB >> 2, kB = (cB & 3) * 8;
    int mrow = lane & 15;
    int kq   = (lane >> 4) * 8;

    for (int kc = 0; kc < Hdim; kc += GBK) {
        __syncthreads();
        gload16(A + (size_t)(m0 + rA) * Hdim + kc + kA, (__bf16*)As + cA * 8);
        gload16(A + (size_t)(m0 + rB) * Hdim + kc + kB, (__bf16*)As + cB * 8);
        gload16(W + (size_t)(n0 + rA) * Hdim + kc + kA, (__bf16*)Ws + cA * 8);
        gload16(W + (size_t)(n0 + rB) * Hdim + kc + kB, (__bf16*)Ws + cB * 8);
        __syncthreads();
        bf16x8 af[4], bf[4];
#pragma unroll
        for (int i = 0; i < 4; ++i)
            af[i] = *(const bf16x8*)&As[wr * 64 + i * 16 + mrow][kq];
#pragma unroll
        for (int j = 0; j < 4; ++j)
            bf[j] = *(const bf16x8*)&Ws[wc * 64 + j * 16 + mrow][kq];
#pragma unroll
        for (int i = 0; i < 4; ++i)
#pragma unroll
            for (int j = 0; j < 4; ++j)
                acc[i][j] = __builtin_amdgcn_mfma_f32_16x16x32_bf16(af[i], bf[j], acc[i][j], 0, 0, 0);
    }

    // epilogue: C/D layout col=lane&15, row=(lane>>4)*4+reg
    int colq = lane & 15;
    int rowq = (lane >> 4) * 4;
#pragma unroll
    for (int i = 0; i < 4; ++i) {
#pragma unroll
        for (int r = 0; r < 4; ++r) {
            int m = m0 + wr * 64 + i * 16 + rowq + r;
            float kf = keepv ? keepv[m] : 1.0f;
#pragma unroll
            for (int j = 0; j < 4; ++j) {
                int n = n0 + wc * 64 + j * 16 + colq;
                float v = acc[i][j][r] + bias[n];
                if (doRelu) v = fmaxf(v, 0.0f);
                if (resid) v += resid[(size_t)m * Hdim + n];
                v *= kf;
                if (outF)  outF[(size_t)m * Hdim + n]  = v;
                if (outBF) outBF[(size_t)m * Hdim + n] = f2bf(v);
                if (outVT) {
                    int bb = m >> 9, l = m & 511;
                    int hh = n >> 6, dd = n & 63;
                    outVT[(((size_t)bb * NHEAD + hh) * HD + dd) * Ldim + l] = f2bf(v);
                }
            }
        }
    }
}

// ---------------- gated causal flash attention, bf16 MFMA ----------------
// grid: (L/64, NHEAD, B), 256 threads = 4 waves; wave w owns q rows 16w..16w+15
__global__ __launch_bounds__(256)
void attn_mfma_kernel(const unsigned short* __restrict__ Qg,
                      const unsigned short* __restrict__ Kg,
                      const unsigned short* __restrict__ VTg,
                      const float* __restrict__ gates,
                      float* __restrict__ Ob, int blk) {
    // padded rows (72 bf16 = 144B): fragment b128 reads are 2-way conflict (free)
    __shared__ __bf16 Qs[64][72];
    __shared__ __bf16 Ks[64][72];
    __shared__ __bf16 VTs[64][72];   // V^T tile: [d][k_local]
    __shared__ __bf16 Ps[64][72];    // P: [q_local][k_local], per-wave 16-row strips
    __shared__ float gks[64];
    int qt = blockIdx.x, h = blockIdx.y, b = blockIdx.z;
    int q0 = qt * 64;
    int tid = threadIdx.x, lane = tid & 63, w = tid >> 6;
    int colq = lane & 15, grp = lane >> 4;
    int rowq = grp * 4, kq = grp * 8;

    size_t baseQO = ((size_t)b * Ldim + q0) * Hdim + h * HD;
    // stage Q tile (64 rows x 64 bf16)
    {
        int c0 = tid, c1 = tid + 256;
        int r0 = c0 >> 3, o0 = (c0 & 7) * 8;
        int r1 = c1 >> 3, o1 = (c1 & 7) * 8;
        *(bf16x8*)&Qs[r0][o0] = *(const bf16x8*)(Qg + baseQO + (size_t)r0 * Hdim + o0);
        *(bf16x8*)&Qs[r1][o1] = *(const bf16x8*)(Qg + baseQO + (size_t)r1 * Hdim + o1);
    }
    float gq[4];
#pragma unroll
    for (int r = 0; r < 4; ++r)
        gq[r] = gates[((size_t)b * Ldim + q0 + w * 16 + rowq + r) * 2 + blk] * 0.125f;
    __syncthreads();
    bf16x8 afq[2];
    afq[0] = *(const bf16x8*)&Qs[w * 16 + colq][kq];
    afq[1] = *(const bf16x8*)&Qs[w * 16 + colq][32 + kq];

    float mrun[4], lrun[4];
    f32x4 accO[4];
#pragma unroll
    for (int r = 0; r < 4; ++r) { mrun[r] = -1e30f; lrun[r] = 0.0f; }
#pragma unroll
    for (int jd = 0; jd < 4; ++jd) accO[jd] = (f32x4)(0.0f);

    for (int kt = 0; kt <= qt; ++kt) {
        int k0 = kt * 64;
        __syncthreads();   // protect Ks/VTs/gks from previous-iteration readers
        {
            size_t baseK = ((size_t)b * Ldim + k0) * Hdim + h * HD;
            size_t baseV = ((size_t)b * NHEAD + h) * HD * Ldim + k0;
            int c0 = tid, c1 = tid + 256;
            int r0 = c0 >> 3, o0 = (c0 & 7) * 8;
            int r1 = c1 >> 3, o1 = (c1 & 7) * 8;
            *(bf16x8*)&Ks[r0][o0]  = *(const bf16x8*)(Kg + baseK + (size_t)r0 * Hdim + o0);
            *(bf16x8*)&Ks[r1][o1]  = *(const bf16x8*)(Kg + baseK + (size_t)r1 * Hdim + o1);
            *(bf16x8*)&VTs[r0][o0] = *(const bf16x8*)(VTg + baseV + (size_t)r0 * Ldim + o0);
            *(bf16x8*)&VTs[r1][o1] = *(const bf16x8*)(VTg + baseV + (size_t)r1 * Ldim + o1);
            if (tid < 64) gks[tid] = gates[((size_t)b * Ldim + k0 + tid) * 2 + blk];
        }
        __syncthreads();

        // S = Q K^T : 4 k-tiles (j), 2 k-dim blocks each
        f32x4 s[4];
#pragma unroll
        for (int j = 0; j < 4; ++j) s[j] = (f32x4)(0.0f);
#pragma unroll
        for (int j = 0; j < 4; ++j) {
            bf16x8 bk0 = *(const bf16x8*)&Ks[j * 16 + colq][kq];
            bf16x8 bk1 = *(const bf16x8*)&Ks[j * 16 + colq][32 + kq];
            s[j] = __builtin_amdgcn_mfma_f32_16x16x32_bf16(afq[0], bk0, s[j], 0, 0, 0);
            s[j] = __builtin_amdgcn_mfma_f32_16x16x32_bf16(afq[1], bk1, s[j], 0, 0, 0);
        }
        bool diag = (kt == qt);
        float gkv[4];
#pragma unroll
        for (int j = 0; j < 4; ++j) gkv[j] = gks[j * 16 + colq];

        // online softmax per owned q-row r; lanes sharing q = 16-lane group
#pragma unroll
        for (int r = 0; r < 4; ++r) {
            float p[4];
            float mx = -1e30f;
#pragma unroll
            for (int j = 0; j < 4; ++j) {
                float v = s[j][r] * gq[r] * gkv[j];
                if (diag && (j * 16 + colq > w * 16 + rowq + r)) v = -1e30f;
                p[j] = v;
                mx = fmaxf(mx, v);
            }
#pragma unroll
            for (int off = 1; off < 16; off <<= 1)
                mx = fmaxf(mx, __shfl_xor(mx, off, 16));
            float mnew = fmaxf(mrun[r], mx);
            float alpha = __expf(mrun[r] - mnew);
            mrun[r] = mnew;
            float su = 0.0f;
#pragma unroll
            for (int j = 0; j < 4; ++j) {
                float e = __expf(p[j] - mnew);
                p[j] = e;
                su += e;
            }
#pragma unroll
            for (int off = 1; off < 16; off <<= 1)
                su += __shfl_xor(su, off, 16);
            lrun[r] = lrun[r] * alpha + su;
#pragma unroll
            for (int jd = 0; jd < 4; ++jd) accO[jd][r] *= alpha;
#pragma unroll
            for (int j = 0; j < 4; ++j)
                Ps[w * 16 + rowq + r][j * 16 + colq] = (__bf16)p[j];
        }

        // O += P V  (A = own wave's P strip; B = V^T tile); within-wave LDS
        // write->read ordering handled by compiler lgkmcnt (no barrier needed:
        // each wave reads only its own 16 Ps rows)
        bf16x8 ap0 = *(const bf16x8*)&Ps[w * 16 + colq][kq];
        bf16x8 ap1 = *(const bf16x8*)&Ps[w * 16 + colq][32 + kq];
#pragma unroll
        for (int jd = 0; jd < 4; ++jd) {
            bf16x8 bv0 = *(const bf16x8*)&VTs[jd * 16 + colq][kq];
            bf16x8 bv1 = *(const bf16x8*)&VTs[jd * 16 + colq][32 + kq];
            accO[jd] = __builtin_amdgcn_mfma_f32_16x16x32_bf16(ap0, bv0, accO[jd], 0, 0, 0);
            accO[jd] = __builtin_amdgcn_mfma_f32_16x16x32_bf16(ap1, bv1, accO[jd], 0, 0, 0);
        }
    }

    // epilogue: O[q][d] f32; lanes 0..15 of a group write 64B contiguous
#pragma unroll
    for (int r = 0; r < 4; ++r) {
        float inv = 1.0f / lrun[r];
#pragma unroll
        for (int jd = 0; jd < 4; ++jd)
            Ob[baseQO + (size_t)(w * 16 + rowq + r) * Hdim + jd * 16 + colq] =
                accO[jd][r] * inv;
    }
}

// ---------------- launcher ----------------
extern "C" void kernel_launch(void* const* d_in, const int* in_sizes, int n_in,
                              void* d_out, int out_size, void* d_ws, size_t ws_size,
                              hipStream_t stream) {
    const int*   seqs_data = (const int*)d_in[0];
    const float* seqs      = (const float*)d_in[1];
    const int*   position  = (const int*)d_in[2];
    const float* time_emb  = (const float*)d_in[3];
    const float* pos_table = (const float*)d_in[4];
    const float* gate_W    = (const float*)d_in[5];
    const float* gate_b    = (const float*)d_in[6];
    const float* ln_attn_g = (const float*)d_in[7];
    const float* ln_attn_b = (const float*)d_in[8];
    const float* qW        = (const float*)d_in[9];
    const float* qb        = (const float*)d_in[10];
    const float* kW        = (const float*)d_in[11];
    const float* kb        = (const float*)d_in[12];
    const float* vW        = (const float*)d_in[13];
    const float* vb        = (const float*)d_in[14];
    const float* ln_ffn_g  = (const float*)d_in[15];
    const float* ln_ffn_b  = (const float*)d_in[16];
    const float* c1W       = (const float*)d_in[17];
    const float* c1b       = (const float*)d_in[18];
    const float* c2W       = (const float*)d_in[19];
    const float* c2b       = (const float*)d_in[20];
    const float* last_g    = (const float*)d_in[21];
    const float* last_b    = (const float*)d_in[22];

    float* S = (float*)d_out;           // evolving seqs in d_out
    size_t BUF = (size_t)NTOK * Hdim;
    float* fws = (float*)d_ws;
    float* T   = fws;                   // time f32 (constant over blocks)
    float* QX  = T + BUF;               // LN out f32 / residual x
    float* QA  = QX + BUF;              // attn out (f32)
    float* GATES = QA + BUF;            // NTOK*2
    float* KEEP  = GATES + (size_t)NTOK * 2;
    unsigned short* bws   = (unsigned short*)(KEEP + NTOK);
    unsigned short* Tbf   = bws;            // bf16(T)
    unsigned short* QXbf  = Tbf + BUF;      // bf16(LN out)
    unsigned short* VINbf = QXbf + BUF;     // bf16(S+T), reused as bf16 hidden
    unsigned short* Qbf   = VINbf + BUF;    // bf16 q
    unsigned short* Kbf   = Qbf + BUF;      // bf16 k
    unsigned short* VTbf  = Kbf + BUF;      // bf16 V^T [B][NH][HD][L]
    unsigned short* Wbf   = VTbf + BUF;     // 10 x 65536 bf16 weights
    size_t WB = (size_t)Hdim * Hdim;        // 65536 per matrix
    unsigned short* qWbf  = Wbf;
    unsigned short* kWbf  = Wbf + 2 * WB;
    unsigned short* vWbf  = Wbf + 4 * WB;
    unsigned short* c1Wbf = Wbf + 6 * WB;
    unsigned short* c2Wbf = Wbf + 8 * WB;

    castw_kernel<<<dim3(128, 5), 256, 0, stream>>>(qW, kW, vW, c1W, c2W, Wbf);
    prep_kernel<<<NTOK, 256, 0, stream>>>(seqs_data, seqs, position, time_emb,
                                          pos_table, gate_W, gate_b,
                                          S, T, Tbf, GATES, KEEP);

    dim3 ggrid(Hdim / GBN, NTOK / GBM);   // (2, 256)
    dim3 agrid(Ldim / 64, NHEAD, Bdim);   // (8, 4, 64)
    for (int i = 0; i < 2; ++i) {
        ln_kernel<<<NTOK, 256, 0, stream>>>(S, nullptr, T, QX, QXbf, VINbf,
                                            ln_attn_g + i * Hdim, ln_attn_b + i * Hdim);
        // q -> bf16, k -> bf16, v -> bf16 transposed
        gemm_bf16_kernel<<<ggrid, 256, 0, stream>>>(QXbf, qWbf + i * WB, qb + i * Hdim,
                                                    nullptr, nullptr, nullptr, Qbf, nullptr, 0);
        gemm_bf16_kernel<<<ggrid, 256, 0, stream>>>(Tbf, kWbf + i * WB, kb + i * Hdim,
                                                    nullptr, nullptr, nullptr, Kbf, nullptr, 0);
        gemm_bf16_kernel<<<ggrid, 256, 0, stream>>>(VINbf, vWbf + i * WB, vb + i * Hdim,
                                                    nullptr, nullptr, nullptr, nullptr, VTbf, 0);
        attn_mfma_kernel<<<agrid, 256, 0, stream>>>(Qbf, Kbf, VTbf, GATES, QA, i);
        ln_kernel<<<NTOK, 256, 0, stream>>>(QX, QA, nullptr, QX, QXbf, nullptr,
                                            ln_ffn_g + i * Hdim, ln_ffn_b + i * Hdim);
        // c1: hidden -> bf16 only (input to c2)
        gemm_bf16_kernel<<<ggrid, 256, 0, stream>>>(QXbf, c1Wbf + i * WB, c1b + i * Hdim,
                                                    nullptr, nullptr, nullptr, VINbf, nullptr, 1);
        // c2: + resid(QX), * keep -> S f32
        gemm_bf16_kernel<<<ggrid, 256, 0, stream>>>(VINbf, c2Wbf + i * WB, c2b + i * Hdim,
                                                    QX, KEEP, S, nullptr, nullptr, 0);
    }
    ln_kernel<<<NTOK, 256, 0, stream>>>(S, nullptr, nullptr, S, nullptr, nullptr,
                                        last_g, last_b);
}

// Round 5
// 512.117 us; speedup vs baseline: 3.8492x; 1.3004x over previous
//
#include <hip/hip_runtime.h>
#include <hip/hip_bf16.h>
#include <math.h>

// Problem constants
#define NTOK 32768      // B*L = 64*512
#define Hdim 256
#define Ldim 512
#define Bdim 64
#define NHEAD 4
#define HD 64
#define PADV 49999      // ITEMNUM-1

typedef __bf16 bf16x8 __attribute__((ext_vector_type(8)));
typedef float  f32x4  __attribute__((ext_vector_type(4)));

__device__ __forceinline__ unsigned short f2bf(float f) {
    unsigned int u = __float_as_uint(f);
    unsigned int r = (u + 0x7fffu + ((u >> 16) & 1u)) >> 16;
    return (unsigned short)r;
}
__device__ __forceinline__ float bf2f(unsigned short u) {
    return __uint_as_float(((unsigned int)u) << 16);
}

// async global->LDS, 16B per lane (dest must be wave-uniform base + lane*16)
__device__ __forceinline__ void gload16(const void* g, void* l) {
    __builtin_amdgcn_global_load_lds((const __attribute__((address_space(1))) unsigned int*)g,
                                     (__attribute__((address_space(3))) unsigned int*)l,
                                     16, 0, 0);
}

// ---------------- weight cast: 5 matrices x (2*256*256) f32 -> bf16 ----------------
__global__ __launch_bounds__(256)
void castw_kernel(const float* __restrict__ q, const float* __restrict__ k,
                  const float* __restrict__ v, const float* __restrict__ c1,
                  const float* __restrict__ c2, unsigned short* __restrict__ dst) {
    const float* srcs[5] = {q, k, v, c1, c2};
    const float* s = srcs[blockIdx.y];
    int idx = blockIdx.x * 1024 + threadIdx.x * 4;
    float4 f = *(const float4*)(s + idx);
    unsigned short* d = dst + (size_t)blockIdx.y * 131072 + idx;
    d[0] = f2bf(f.x); d[1] = f2bf(f.y); d[2] = f2bf(f.z); d[3] = f2bf(f.w);
}

// ---------------- prep + ln_attn[0] fused (wave per token) ----------------
__global__ __launch_bounds__(256)
void prep_ln_kernel(const int* __restrict__ seqs_data, const float* __restrict__ seqs,
                    const int* __restrict__ position, const float* __restrict__ time_emb,
                    const float* __restrict__ pos_table, const float* __restrict__ gate_W,
                    const float* __restrict__ gate_b,
                    const float* __restrict__ lnG, const float* __restrict__ lnB,
                    float* __restrict__ T, unsigned short* __restrict__ Tbf,
                    float* __restrict__ QX, unsigned short* __restrict__ QXbf,
                    unsigned short* __restrict__ VINbf,
                    float* __restrict__ gates, float* __restrict__ keepv) {
    int tok  = blockIdx.x * 4 + (threadIdx.x >> 6);
    int lane = threadIdx.x & 63;
    size_t off = (size_t)tok * Hdim + lane * 4;
    int pos = position[tok];
    float4 pe = *(const float4*)(pos_table + (size_t)pos * Hdim + lane * 4);
    float4 sq = *(const float4*)(seqs + off);
    float4 tm = *(const float4*)(time_emb + off);
    float keep = (seqs_data[tok] != PADV) ? 1.0f : 0.0f;
    float4 t = {tm.x + pe.x, tm.y + pe.y, tm.z + pe.z, tm.w + pe.w};
    float4 s = {(sq.x + pe.x) * keep, (sq.y + pe.y) * keep,
                (sq.z + pe.z) * keep, (sq.w + pe.w) * keep};
    *(float4*)(T + off) = t;
    ushort4 tb = {f2bf(t.x), f2bf(t.y), f2bf(t.z), f2bf(t.w)};
    *(ushort4*)(Tbf + off) = tb;
    float4 gw0 = *(const float4*)(gate_W + lane * 4);
    float4 gw1 = *(const float4*)(gate_W + Hdim + lane * 4);
    float r0 = s.x + s.y + s.z + s.w;
    float r1 = s.x * s.x + s.y * s.y + s.z * s.z + s.w * s.w;
    float r2 = t.x * gw0.x + t.y * gw0.y + t.z * gw0.z + t.w * gw0.w;
    float r3 = t.x * gw1.x + t.y * gw1.y + t.z * gw1.z + t.w * gw1.w;
#pragma unroll
    for (int o = 1; o < 64; o <<= 1) {
        r0 += __shfl_xor(r0, o, 64);
        r1 += __shfl_xor(r1, o, 64);
        r2 += __shfl_xor(r2, o, 64);
        r3 += __shfl_xor(r3, o, 64);
    }
    float mean = r0 * (1.0f / Hdim);
    float var  = fmaxf(r1 * (1.0f / Hdim) - mean * mean, 0.0f);
    float rstd = rsqrtf(var + 1e-8f);
    if (lane == 0) {
        gates[(size_t)tok * 2 + 0] = 1.0f / (1.0f + __expf(-(r2 + gate_b[0])));
        gates[(size_t)tok * 2 + 1] = 1.0f / (1.0f + __expf(-(r3 + gate_b[1])));
        keepv[tok] = keep;
    }
    float4 g4 = *(const float4*)(lnG + lane * 4);
    float4 b4 = *(const float4*)(lnB + lane * 4);
    float4 y = {(s.x - mean) * rstd * g4.x + b4.x, (s.y - mean) * rstd * g4.y + b4.y,
                (s.z - mean) * rstd * g4.z + b4.z, (s.w - mean) * rstd * g4.w + b4.w};
    *(float4*)(QX + off) = y;
    ushort4 yb = {f2bf(y.x), f2bf(y.y), f2bf(y.z), f2bf(y.w)};
    *(ushort4*)(QXbf + off) = yb;
    ushort4 vb = {f2bf(s.x + t.x), f2bf(s.y + t.y), f2bf(s.z + t.z), f2bf(s.w + t.w)};
    *(ushort4*)(VINbf + off) = vb;
}

// ---------------- ln_ffn: x = QX + bf16(QA); LN -> QX, QXbf (wave per token) ----------------
__global__ __launch_bounds__(256)
void ln2_kernel(float* QX, const unsigned short* __restrict__ QA,
                unsigned short* __restrict__ QXbf,
                const float* __restrict__ lnG, const float* __restrict__ lnB) {
    int tok  = blockIdx.x * 4 + (threadIdx.x >> 6);
    int lane = threadIdx.x & 63;
    size_t off = (size_t)tok * Hdim + lane * 4;
    float4 x = *(const float4*)(QX + off);
    ushort4 a = *(const ushort4*)(QA + off);
    x.x += bf2f(a.x); x.y += bf2f(a.y); x.z += bf2f(a.z); x.w += bf2f(a.w);
    float r0 = x.x + x.y + x.z + x.w;
    float r1 = x.x * x.x + x.y * x.y + x.z * x.z + x.w * x.w;
#pragma unroll
    for (int o = 1; o < 64; o <<= 1) {
        r0 += __shfl_xor(r0, o, 64);
        r1 += __shfl_xor(r1, o, 64);
    }
    float mean = r0 * (1.0f / Hdim);
    float var  = fmaxf(r1 * (1.0f / Hdim) - mean * mean, 0.0f);
    float rstd = rsqrtf(var + 1e-8f);
    float4 g4 = *(const float4*)(lnG + lane * 4);
    float4 b4 = *(const float4*)(lnB + lane * 4);
    float4 y = {(x.x - mean) * rstd * g4.x + b4.x, (x.y - mean) * rstd * g4.y + b4.y,
                (x.z - mean) * rstd * g4.z + b4.z, (x.w - mean) * rstd * g4.w + b4.w};
    *(float4*)(QX + off) = y;
    ushort4 yb = {f2bf(y.x), f2bf(y.y), f2bf(y.z), f2bf(y.w)};
    *(ushort4*)(QXbf + off) = yb;
}

// ---------------- plain bf16 GEMM 128x128: C = A@W^T + bias [relu] -> bf16 ----------------
#define GBM 128
#define GBN 128
#define GBK 32
__global__ __launch_bounds__(256)
void gemm_plain_kernel(const unsigned short* __restrict__ A,
                       const unsigned short* __restrict__ W,
                       const float* __restrict__ bias,
                       unsigned short* __restrict__ outBF, int doRelu) {
    __shared__ __bf16 As[GBM][GBK];
    __shared__ __bf16 Ws[GBN][GBK];
    int tid = threadIdx.x, lane = tid & 63, w = tid >> 6;
    int wr = w >> 1, wc = w & 1;
    int m0 = blockIdx.y * GBM, n0 = blockIdx.x * GBN;
    f32x4 acc[4][4];
#pragma unroll
    for (int i = 0; i < 4; ++i)
#pragma unroll
        for (int j = 0; j < 4; ++j) acc[i][j] = (f32x4)(0.0f);
    int cA = tid, cB = tid + 256;
    int rA = cA >> 2, kA = (cA & 3) * 8;
    int rB = cB >> 2, kB = (cB & 3) * 8;
    int colq = lane & 15, kq = (lane >> 4) * 8;
    for (int kc = 0; kc < Hdim; kc += GBK) {
        __syncthreads();
        gload16(A + (size_t)(m0 + rA) * Hdim + kc + kA, (__bf16*)As + cA * 8);
        gload16(A + (size_t)(m0 + rB) * Hdim + kc + kB, (__bf16*)As + cB * 8);
        gload16(W + (size_t)(n0 + rA) * Hdim + kc + kA, (__bf16*)Ws + cA * 8);
        gload16(W + (size_t)(n0 + rB) * Hdim + kc + kB, (__bf16*)Ws + cB * 8);
        __syncthreads();
        bf16x8 af[4], bfr[4];
#pragma unroll
        for (int i = 0; i < 4; ++i)
            af[i] = *(const bf16x8*)&As[wr * 64 + i * 16 + colq][kq];
#pragma unroll
        for (int j = 0; j < 4; ++j)
            bfr[j] = *(const bf16x8*)&Ws[wc * 64 + j * 16 + colq][kq];
#pragma unroll
        for (int i = 0; i < 4; ++i)
#pragma unroll
            for (int j = 0; j < 4; ++j)
                acc[i][j] = __builtin_amdgcn_mfma_f32_16x16x32_bf16(af[i], bfr[j], acc[i][j], 0, 0, 0);
    }
    int rowq = (lane >> 4) * 4;
#pragma unroll
    for (int i = 0; i < 4; ++i)
#pragma unroll
        for (int r = 0; r < 4; ++r) {
            int m = m0 + wr * 64 + i * 16 + rowq + r;
#pragma unroll
            for (int j = 0; j < 4; ++j) {
                int n = n0 + wc * 64 + j * 16 + colq;
                float v = acc[i][j][r] + bias[n];
                if (doRelu) v = fmaxf(v, 0.0f);
                outBF[(size_t)m * Hdim + n] = f2bf(v);
            }
        }
}

// ---------------- v GEMM 128x128 with LDS-transposed V^T output ----------------
// VT layout [B][NH][HD][L] bf16, coalesced 16B writes
// Ct rows padded to 136 elems (272B = 17*16) so every row base is 16B-aligned
__global__ __launch_bounds__(256)
void gemm_vt_kernel(const unsigned short* __restrict__ A,
                    const unsigned short* __restrict__ W,
                    const float* __restrict__ bias,
                    unsigned short* __restrict__ VT) {
    __shared__ __bf16 As[GBM][GBK];
    __shared__ __bf16 Ws[GBN][GBK];
    __shared__ __bf16 Ct[128][136];
    int tid = threadIdx.x, lane = tid & 63, w = tid >> 6;
    int wr = w >> 1, wc = w & 1;
    int m0 = blockIdx.y * GBM, n0 = blockIdx.x * GBN;
    f32x4 acc[4][4];
#pragma unroll
    for (int i = 0; i < 4; ++i)
#pragma unroll
        for (int j = 0; j < 4; ++j) acc[i][j] = (f32x4)(0.0f);
    int cA = tid, cB = tid + 256;
    int rA = cA >> 2, kA = (cA & 3) * 8;
    int rB = cB >> 2, kB = (cB & 3) * 8;
    int colq = lane & 15, kq = (lane >> 4) * 8;
    for (int kc = 0; kc < Hdim; kc += GBK) {
        __syncthreads();
        gload16(A + (size_t)(m0 + rA) * Hdim + kc + kA, (__bf16*)As + cA * 8);
        gload16(A + (size_t)(m0 + rB) * Hdim + kc + kB, (__bf16*)As + cB * 8);
        gload16(W + (size_t)(n0 + rA) * Hdim + kc + kA, (__bf16*)Ws + cA * 8);
        gload16(W + (size_t)(n0 + rB) * Hdim + kc + kB, (__bf16*)Ws + cB * 8);
        __syncthreads();
        bf16x8 af[4], bfr[4];
#pragma unroll
        for (int i = 0; i < 4; ++i)
            af[i] = *(const bf16x8*)&As[wr * 64 + i * 16 + colq][kq];
#pragma unroll
        for (int j = 0; j < 4; ++j)
            bfr[j] = *(const bf16x8*)&Ws[wc * 64 + j * 16 + colq][kq];
#pragma unroll
        for (int i = 0; i < 4; ++i)
#pragma unroll
            for (int j = 0; j < 4; ++j)
                acc[i][j] = __builtin_amdgcn_mfma_f32_16x16x32_bf16(af[i], bfr[j], acc[i][j], 0, 0, 0);
    }
    __syncthreads();
    int rowq = (lane >> 4) * 4;
#pragma unroll
    for (int i = 0; i < 4; ++i)
#pragma unroll
        for (int r = 0; r < 4; ++r) {
            int ml = wr * 64 + i * 16 + rowq + r;
#pragma unroll
            for (int j = 0; j < 4; ++j) {
                int nl = wc * 64 + j * 16 + colq;
                // direct float->bf16 value conversion (NOT f2bf bit-pattern cast)
                Ct[nl][ml] = (__bf16)(acc[i][j][r] + bias[n0 + nl]);
            }
        }
    __syncthreads();
    int bb = m0 >> 9, l0 = m0 & 511;
#pragma unroll
    for (int it = 0; it < 8; ++it) {
        int c = tid + it * 256;          // 0..2047
        int nl = c >> 4;                 // 0..127
        int o8 = (c & 15) * 8;           // element offset in m
        int n = n0 + nl;
        int hh = n >> 6, dd = n & 63;
        bf16x8 v = *(const bf16x8*)&Ct[nl][o8];
        *(bf16x8*)(VT + ((((size_t)bb * NHEAD + hh) * HD + dd) * Ldim + l0 + o8)) = v;
    }
}

// ---------------- c2 GEMM 64x256 + resid + keep + row-LN epilogue ----------------
__global__ __launch_bounds__(256)
void gemm_c2ln_kernel(const unsigned short* __restrict__ A,   // hidden bf16
                      const unsigned short* __restrict__ W,   // c2W bf16
                      const float* __restrict__ bias,
                      float* residQX,                          // read resid
                      const float* __restrict__ keepv,
                      const float* __restrict__ lnG, const float* __restrict__ lnB,
                      const float* __restrict__ Tf,            // nullable (for VIN)
                      float* outF,                             // QX or d_out
                      unsigned short* __restrict__ outBF,      // nullable
                      unsigned short* __restrict__ outVIN) {   // nullable
    __shared__ __bf16 As[64][32];      // 4 KB
    __shared__ __bf16 Ws[256][32];     // 16 KB
    __shared__ float red[4][64][2];    // 2 KB
    int tid = threadIdx.x, lane = tid & 63, w = tid >> 6;
    int colq = lane & 15, grp = lane >> 4, rowq = grp * 4, kq = grp * 8;
    int m0 = blockIdx.x * 64;
    f32x4 acc[4][4];
#pragma unroll
    for (int i = 0; i < 4; ++i)
#pragma unroll
        for (int j = 0; j < 4; ++j) acc[i][j] = (f32x4)(0.0f);
    for (int kc = 0; kc < Hdim; kc += 32) {
        __syncthreads();
        gload16(A + (size_t)(m0 + (tid >> 2)) * Hdim + kc + (tid & 3) * 8,
                (__bf16*)As + tid * 8);
#pragma unroll
        for (int it = 0; it < 4; ++it) {
            int c = tid + it * 256;
            gload16(W + (size_t)(c >> 2) * Hdim + kc + (c & 3) * 8, (__bf16*)Ws + c * 8);
        }
        __syncthreads();
        bf16x8 af[4], bfr[4];
#pragma unroll
        for (int i = 0; i < 4; ++i)
            af[i] = *(const bf16x8*)&As[i * 16 + colq][kq];
#pragma unroll
        for (int j = 0; j < 4; ++j)
            bfr[j] = *(const bf16x8*)&Ws[w * 64 + j * 16 + colq][kq];
#pragma unroll
        for (int i = 0; i < 4; ++i)
#pragma unroll
            for (int j = 0; j < 4; ++j)
                acc[i][j] = __builtin_amdgcn_mfma_f32_16x16x32_bf16(af[i], bfr[j], acc[i][j], 0, 0, 0);
    }
    // epilogue: S_new = (acc + bias + resid) * keep
#pragma unroll
    for (int i = 0; i < 4; ++i)
#pragma unroll
        for (int r = 0; r < 4; ++r) {
            int m = m0 + i * 16 + rowq + r;
            float kf = keepv[m];
#pragma unroll
            for (int j = 0; j < 4; ++j) {
                int nl = w * 64 + j * 16 + colq;
                float v = acc[i][j][r] + bias[nl] + residQX[(size_t)m * Hdim + nl];
                acc[i][j][r] = v * kf;
            }
        }
    // row stats: per-wave partial over its 64 cols, then cross-wave via LDS
#pragma unroll
    for (int i = 0; i < 4; ++i)
#pragma unroll
        for (int r = 0; r < 4; ++r) {
            float s1 = acc[i][0][r] + acc[i][1][r] + acc[i][2][r] + acc[i][3][r];
            float s2 = acc[i][0][r] * acc[i][0][r] + acc[i][1][r] * acc[i][1][r] +
                       acc[i][2][r] * acc[i][2][r] + acc[i][3][r] * acc[i][3][r];
#pragma unroll
            for (int o = 1; o < 16; o <<= 1) {
                s1 += __shfl_xor(s1, o, 64);
                s2 += __shfl_xor(s2, o, 64);
            }
            if (colq == 0) {
                red[w][i * 16 + rowq + r][0] = s1;
                red[w][i * 16 + rowq + r][1] = s2;
            }
        }
    __syncthreads();
    float mean_[4][4], rstd_[4][4];
#pragma unroll
    for (int i = 0; i < 4; ++i)
#pragma unroll
        for (int r = 0; r < 4; ++r) {
            int row = i * 16 + rowq + r;
            float s1 = red[0][row][0] + red[1][row][0] + red[2][row][0] + red[3][row][0];
            float s2 = red[0][row][1] + red[1][row][1] + red[2][row][1] + red[3][row][1];
            float mean = s1 * (1.0f / Hdim);
            float var  = fmaxf(s2 * (1.0f / Hdim) - mean * mean, 0.0f);
            mean_[i][r] = mean;
            rstd_[i][r] = rsqrtf(var + 1e-8f);
        }
#pragma unroll
    for (int i = 0; i < 4; ++i)
#pragma unroll
        for (int r = 0; r < 4; ++r) {
            int m = m0 + i * 16 + rowq + r;
#pragma unroll
            for (int j = 0; j < 4; ++j) {
                int nl = w * 64 + j * 16 + colq;
                float v = acc[i][j][r];
                float y = (v - mean_[i][r]) * rstd_[i][r] * lnG[nl] + lnB[nl];
                outF[(size_t)m * Hdim + nl] = y;
                if (outBF)  outBF[(size_t)m * Hdim + nl]  = f2bf(y);
                if (outVIN) outVIN[(size_t)m * Hdim + nl] =
                    f2bf(v + Tf[(size_t)m * Hdim + nl]);
            }
        }
}

// ---------------- gated causal flash attention, bf16 MFMA ----------------
__global__ __launch_bounds__(256)
void attn_mfma_kernel(const unsigned short* __restrict__ Qg,
                      const unsigned short* __restrict__ Kg,
                      const unsigned short* __restrict__ VTg,
                      const float* __restrict__ gates,
                      unsigned short* __restrict__ Ob, int blk) {
    __shared__ __bf16 Qs[64][72];
    __shared__ __bf16 Ks[64][72];
    __shared__ __bf16 VTs[64][72];
    __shared__ __bf16 Ps[64][72];
    __shared__ float gks[64];
    int qt = blockIdx.x, h = blockIdx.y, b = blockIdx.z;
    int q0 = qt * 64;
    int tid = threadIdx.x, lane = tid & 63, w = tid >> 6;
    int colq = lane & 15, grp = lane >> 4;
    int rowq = grp * 4, kq = grp * 8;
    size_t baseQO = ((size_t)b * Ldim + q0) * Hdim + h * HD;
    {
        int c0 = tid, c1 = tid + 256;
        int r0 = c0 >> 3, o0 = (c0 & 7) * 8;
        int r1 = c1 >> 3, o1 = (c1 & 7) * 8;
        *(bf16x8*)&Qs[r0][o0] = *(const bf16x8*)(Qg + baseQO + (size_t)r0 * Hdim + o0);
        *(bf16x8*)&Qs[r1][o1] = *(const bf16x8*)(Qg + baseQO + (size_t)r1 * Hdim + o1);
    }
    float gq[4];
#pragma unroll
    for (int r = 0; r < 4; ++r)
        gq[r] = gates[((size_t)b * Ldim + q0 + w * 16 + rowq + r) * 2 + blk] * 0.125f;
    __syncthreads();
    bf16x8 afq[2];
    afq[0] = *(const bf16x8*)&Qs[w * 16 + colq][kq];
    afq[1] = *(const bf16x8*)&Qs[w * 16 + colq][32 + kq];

    float mrun[4], lrun[4];
    f32x4 accO[4];
#pragma unroll
    for (int r = 0; r < 4; ++r) { mrun[r] = -1e30f; lrun[r] = 0.0f; }
#pragma unroll
    for (int jd = 0; jd < 4; ++jd) accO[jd] = (f32x4)(0.0f);

    for (int kt = 0; kt <= qt; ++kt) {
        int k0 = kt * 64;
        __syncthreads();
        {
            size_t baseK = ((size_t)b * Ldim + k0) * Hdim + h * HD;
            size_t baseV = ((size_t)b * NHEAD + h) * HD * Ldim + k0;
            int c0 = tid, c1 = tid + 256;
            int r0 = c0 >> 3, o0 = (c0 & 7) * 8;
            int r1 = c1 >> 3, o1 = (c1 & 7) * 8;
            *(bf16x8*)&Ks[r0][o0]  = *(const bf16x8*)(Kg + baseK + (size_t)r0 * Hdim + o0);
            *(bf16x8*)&Ks[r1][o1]  = *(const bf16x8*)(Kg + baseK + (size_t)r1 * Hdim + o1);
            *(bf16x8*)&VTs[r0][o0] = *(const bf16x8*)(VTg + baseV + (size_t)r0 * Ldim + o0);
            *(bf16x8*)&VTs[r1][o1] = *(const bf16x8*)(VTg + baseV + (size_t)r1 * Ldim + o1);
            if (tid < 64) gks[tid] = gates[((size_t)b * Ldim + k0 + tid) * 2 + blk];
        }
        __syncthreads();

        f32x4 s[4];
#pragma unroll
        for (int j = 0; j < 4; ++j) s[j] = (f32x4)(0.0f);
#pragma unroll
        for (int j = 0; j < 4; ++j) {
            bf16x8 bk0 = *(const bf16x8*)&Ks[j * 16 + colq][kq];
            bf16x8 bk1 = *(const bf16x8*)&Ks[j * 16 + colq][32 + kq];
            s[j] = __builtin_amdgcn_mfma_f32_16x16x32_bf16(afq[0], bk0, s[j], 0, 0, 0);
            s[j] = __builtin_amdgcn_mfma_f32_16x16x32_bf16(afq[1], bk1, s[j], 0, 0, 0);
        }
        bool diag = (kt == qt);
        float gkv[4];
#pragma unroll
        for (int j = 0; j < 4; ++j) gkv[j] = gks[j * 16 + colq];

#pragma unroll
        for (int r = 0; r < 4; ++r) {
            float p[4];
            float mx = -1e30f;
#pragma unroll
            for (int j = 0; j < 4; ++j) {
                float v = s[j][r] * gq[r] * gkv[j];
                if (diag && (j * 16 + colq > w * 16 + rowq + r)) v = -1e30f;
                p[j] = v;
                mx = fmaxf(mx, v);
            }
#pragma unroll
            for (int off = 1; off < 16; off <<= 1)
                mx = fmaxf(mx, __shfl_xor(mx, off, 16));
            float mnew = fmaxf(mrun[r], mx);
            float alpha = __expf(mrun[r] - mnew);
            mrun[r] = mnew;
            float su = 0.0f;
#pragma unroll
            for (int j = 0; j < 4; ++j) {
                float e = __expf(p[j] - mnew);
                p[j] = e;
                su += e;
            }
#pragma unroll
            for (int off = 1; off < 16; off <<= 1)
                su += __shfl_xor(su, off, 16);
            lrun[r] = lrun[r] * alpha + su;
#pragma unroll
            for (int jd = 0; jd < 4; ++jd) accO[jd][r] *= alpha;
#pragma unroll
            for (int j = 0; j < 4; ++j)
                Ps[w * 16 + rowq + r][j * 16 + colq] = (__bf16)p[j];
        }

        bf16x8 ap0 = *(const bf16x8*)&Ps[w * 16 + colq][kq];
        bf16x8 ap1 = *(const bf16x8*)&Ps[w * 16 + colq][32 + kq];
#pragma unroll
        for (int jd = 0; jd < 4; ++jd) {
            bf16x8 bv0 = *(const bf16x8*)&VTs[jd * 16 + colq][kq];
            bf16x8 bv1 = *(const bf16x8*)&VTs[jd * 16 + colq][32 + kq];
            accO[jd] = __builtin_amdgcn_mfma_f32_16x16x32_bf16(ap0, bv0, accO[jd], 0, 0, 0);
            accO[jd] = __builtin_amdgcn_mfma_f32_16x16x32_bf16(ap1, bv1, accO[jd], 0, 0, 0);
        }
    }
#pragma unroll
    for (int r = 0; r < 4; ++r) {
        float inv = 1.0f / lrun[r];
#pragma unroll
        for (int jd = 0; jd < 4; ++jd)
            Ob[baseQO + (size_t)(w * 16 + rowq + r) * Hdim + jd * 16 + colq] =
                f2bf(accO[jd][r] * inv);
    }
}

// ---------------- launcher ----------------
extern "C" void kernel_launch(void* const* d_in, const int* in_sizes, int n_in,
                              void* d_out, int out_size, void* d_ws, size_t ws_size,
                              hipStream_t stream) {
    const int*   seqs_data = (const int*)d_in[0];
    const float* seqs      = (const float*)d_in[1];
    const int*   position  = (const int*)d_in[2];
    const float* time_emb  = (const float*)d_in[3];
    const float* pos_table = (const float*)d_in[4];
    const float* gate_W    = (const float*)d_in[5];
    const float* gate_b    = (const float*)d_in[6];
    const float* ln_attn_g = (const float*)d_in[7];
    const float* ln_attn_b = (const float*)d_in[8];
    const float* qW        = (const float*)d_in[9];
    const float* qb        = (const float*)d_in[10];
    const float* kW        = (const float*)d_in[11];
    const float* kb        = (const float*)d_in[12];
    const float* vW        = (const float*)d_in[13];
    const float* vb        = (const float*)d_in[14];
    const float* ln_ffn_g  = (const float*)d_in[15];
    const float* ln_ffn_b  = (const float*)d_in[16];
    const float* c1W       = (const float*)d_in[17];
    const float* c1b       = (const float*)d_in[18];
    const float* c2W       = (const float*)d_in[19];
    const float* c2b       = (const float*)d_in[20];
    const float* last_g    = (const float*)d_in[21];
    const float* last_b    = (const float*)d_in[22];

    size_t BUF = (size_t)NTOK * Hdim;
    float* fws = (float*)d_ws;
    float* T     = fws;                       // f32 time
    float* QX    = T + BUF;                   // f32 LN-out / resid
    float* GATES = QX + BUF;                  // NTOK*2
    float* KEEP  = GATES + (size_t)NTOK * 2;  // NTOK
    unsigned short* bws   = (unsigned short*)(KEEP + NTOK);
    unsigned short* Tbf   = bws;
    unsigned short* QXbf  = Tbf + BUF;
    unsigned short* VINbf = QXbf + BUF;       // bf16(S+T) input to v-gemm
    unsigned short* HIDbf = VINbf + BUF;      // ffn hidden
    unsigned short* Qbf   = HIDbf + BUF;
    unsigned short* Kbf   = Qbf + BUF;
    unsigned short* VTbf  = Kbf + BUF;        // V^T [B][NH][HD][L]
    unsigned short* QAbf  = VTbf + BUF;       // attn out bf16
    unsigned short* Wbf   = QAbf + BUF;       // 10 x 65536 bf16 weights
    size_t WB = (size_t)Hdim * Hdim;
    unsigned short* qWbf  = Wbf;
    unsigned short* kWbf  = Wbf + 2 * WB;
    unsigned short* vWbf  = Wbf + 4 * WB;
    unsigned short* c1Wbf = Wbf + 6 * WB;
    unsigned short* c2Wbf = Wbf + 8 * WB;

    castw_kernel<<<dim3(128, 5), 256, 0, stream>>>(qW, kW, vW, c1W, c2W, Wbf);
    prep_ln_kernel<<<NTOK / 4, 256, 0, stream>>>(seqs_data, seqs, position, time_emb,
                                                 pos_table, gate_W, gate_b,
                                                 ln_attn_g, ln_attn_b,
                                                 T, Tbf, QX, QXbf, VINbf, GATES, KEEP);

    dim3 ggrid(Hdim / GBN, NTOK / GBM);   // (2, 256)
    dim3 agrid(Ldim / 64, NHEAD, Bdim);   // (8, 4, 64)
    for (int i = 0; i < 2; ++i) {
        gemm_plain_kernel<<<ggrid, 256, 0, stream>>>(QXbf, qWbf + i * WB, qb + i * Hdim, Qbf, 0);
        gemm_plain_kernel<<<ggrid, 256, 0, stream>>>(Tbf,  kWbf + i * WB, kb + i * Hdim, Kbf, 0);
        gemm_vt_kernel<<<ggrid, 256, 0, stream>>>(VINbf, vWbf + i * WB, vb + i * Hdim, VTbf);
        attn_mfma_kernel<<<agrid, 256, 0, stream>>>(Qbf, Kbf, VTbf, GATES, QAbf, i);
        ln2_kernel<<<NTOK / 4, 256, 0, stream>>>(QX, QAbf, QXbf,
                                                 ln_ffn_g + i * Hdim, ln_ffn_b + i * Hdim);
        gemm_plain_kernel<<<ggrid, 256, 0, stream>>>(QXbf, c1Wbf + i * WB, c1b + i * Hdim, HIDbf, 1);
        if (i == 0) {
            gemm_c2ln_kernel<<<NTOK / 64, 256, 0, stream>>>(
                HIDbf, c2Wbf, c2b, QX, KEEP,
                ln_attn_g + Hdim, ln_attn_b + Hdim, T,
                QX, QXbf, VINbf);
        } else {
            gemm_c2ln_kernel<<<NTOK / 64, 256, 0, stream>>>(
                HIDbf, c2Wbf + WB, c2b + Hdim, QX, KEEP,
                last_g, last_b, nullptr,
                (float*)d_out, nullptr, nullptr);
        }
    }
}

// Round 6
// 480.209 us; speedup vs baseline: 4.1050x; 1.0664x over previous
//
#include <hip/hip_runtime.h>
#include <hip/hip_bf16.h>
#include <math.h>

// Problem constants
#define NTOK 32768      // B*L = 64*512
#define Hdim 256
#define Ldim 512
#define Bdim 64
#define NHEAD 4
#define HD 64
#define PADV 49999      // ITEMNUM-1

typedef __bf16 bf16x8 __attribute__((ext_vector_type(8)));
typedef float  f32x4  __attribute__((ext_vector_type(4)));

__device__ __forceinline__ unsigned short f2bf(float f) {
    unsigned int u = __float_as_uint(f);
    unsigned int r = (u + 0x7fffu + ((u >> 16) & 1u)) >> 16;
    return (unsigned short)r;
}
__device__ __forceinline__ float bf2f(unsigned short u) {
    return __uint_as_float(((unsigned int)u) << 16);
}

// async global->LDS, 16B per lane (dest must be wave-uniform base + lane*16)
__device__ __forceinline__ void gload16(const void* g, void* l) {
    __builtin_amdgcn_global_load_lds((const __attribute__((address_space(1))) unsigned int*)g,
                                     (__attribute__((address_space(3))) unsigned int*)l,
                                     16, 0, 0);
}

// ---------------- weight cast: 5 matrices x (2*256*256) f32 -> bf16 ----------------
__global__ __launch_bounds__(256)
void castw_kernel(const float* __restrict__ q, const float* __restrict__ k,
                  const float* __restrict__ v, const float* __restrict__ c1,
                  const float* __restrict__ c2, unsigned short* __restrict__ dst) {
    const float* srcs[5] = {q, k, v, c1, c2};
    const float* s = srcs[blockIdx.y];
    int idx = blockIdx.x * 1024 + threadIdx.x * 4;
    float4 f = *(const float4*)(s + idx);
    unsigned short* d = dst + (size_t)blockIdx.y * 131072 + idx;
    d[0] = f2bf(f.x); d[1] = f2bf(f.y); d[2] = f2bf(f.z); d[3] = f2bf(f.w);
}

// ---------------- prep + ln_attn[0] fused (wave per token) ----------------
__global__ __launch_bounds__(256)
void prep_ln_kernel(const int* __restrict__ seqs_data, const float* __restrict__ seqs,
                    const int* __restrict__ position, const float* __restrict__ time_emb,
                    const float* __restrict__ pos_table, const float* __restrict__ gate_W,
                    const float* __restrict__ gate_b,
                    const float* __restrict__ lnG, const float* __restrict__ lnB,
                    unsigned short* __restrict__ Tbf,
                    float* __restrict__ QX, unsigned short* __restrict__ QXbf,
                    unsigned short* __restrict__ VINbf,
                    float* __restrict__ gates, float* __restrict__ keepv) {
    int tok  = blockIdx.x * 4 + (threadIdx.x >> 6);
    int lane = threadIdx.x & 63;
    size_t off = (size_t)tok * Hdim + lane * 4;
    int pos = position[tok];
    float4 pe = *(const float4*)(pos_table + (size_t)pos * Hdim + lane * 4);
    float4 sq = *(const float4*)(seqs + off);
    float4 tm = *(const float4*)(time_emb + off);
    float keep = (seqs_data[tok] != PADV) ? 1.0f : 0.0f;
    float4 t = {tm.x + pe.x, tm.y + pe.y, tm.z + pe.z, tm.w + pe.w};
    float4 s = {(sq.x + pe.x) * keep, (sq.y + pe.y) * keep,
                (sq.z + pe.z) * keep, (sq.w + pe.w) * keep};
    ushort4 tb = {f2bf(t.x), f2bf(t.y), f2bf(t.z), f2bf(t.w)};
    *(ushort4*)(Tbf + off) = tb;
    float4 gw0 = *(const float4*)(gate_W + lane * 4);
    float4 gw1 = *(const float4*)(gate_W + Hdim + lane * 4);
    float r0 = s.x + s.y + s.z + s.w;
    float r1 = s.x * s.x + s.y * s.y + s.z * s.z + s.w * s.w;
    float r2 = t.x * gw0.x + t.y * gw0.y + t.z * gw0.z + t.w * gw0.w;
    float r3 = t.x * gw1.x + t.y * gw1.y + t.z * gw1.z + t.w * gw1.w;
#pragma unroll
    for (int o = 1; o < 64; o <<= 1) {
        r0 += __shfl_xor(r0, o, 64);
        r1 += __shfl_xor(r1, o, 64);
        r2 += __shfl_xor(r2, o, 64);
        r3 += __shfl_xor(r3, o, 64);
    }
    float mean = r0 * (1.0f / Hdim);
    float var  = fmaxf(r1 * (1.0f / Hdim) - mean * mean, 0.0f);
    float rstd = rsqrtf(var + 1e-8f);
    if (lane == 0) {
        gates[(size_t)tok * 2 + 0] = 1.0f / (1.0f + __expf(-(r2 + gate_b[0])));
        gates[(size_t)tok * 2 + 1] = 1.0f / (1.0f + __expf(-(r3 + gate_b[1])));
        keepv[tok] = keep;
    }
    float4 g4 = *(const float4*)(lnG + lane * 4);
    float4 b4 = *(const float4*)(lnB + lane * 4);
    float4 y = {(s.x - mean) * rstd * g4.x + b4.x, (s.y - mean) * rstd * g4.y + b4.y,
                (s.z - mean) * rstd * g4.z + b4.z, (s.w - mean) * rstd * g4.w + b4.w};
    *(float4*)(QX + off) = y;
    ushort4 yb = {f2bf(y.x), f2bf(y.y), f2bf(y.z), f2bf(y.w)};
    *(ushort4*)(QXbf + off) = yb;
    ushort4 vb = {f2bf(s.x + t.x), f2bf(s.y + t.y), f2bf(s.z + t.z), f2bf(s.w + t.w)};
    *(ushort4*)(VINbf + off) = vb;
}

// ---------------- ln_ffn: x = QX + bf16(QA); LN -> QX, QXbf (wave per token) ----------------
__global__ __launch_bounds__(256)
void ln2_kernel(float* QX, const unsigned short* __restrict__ QA,
                unsigned short* __restrict__ QXbf,
                const float* __restrict__ lnG, const float* __restrict__ lnB) {
    int tok  = blockIdx.x * 4 + (threadIdx.x >> 6);
    int lane = threadIdx.x & 63;
    size_t off = (size_t)tok * Hdim + lane * 4;
    float4 x = *(const float4*)(QX + off);
    ushort4 a = *(const ushort4*)(QA + off);
    x.x += bf2f(a.x); x.y += bf2f(a.y); x.z += bf2f(a.z); x.w += bf2f(a.w);
    float r0 = x.x + x.y + x.z + x.w;
    float r1 = x.x * x.x + x.y * x.y + x.z * x.z + x.w * x.w;
#pragma unroll
    for (int o = 1; o < 64; o <<= 1) {
        r0 += __shfl_xor(r0, o, 64);
        r1 += __shfl_xor(r1, o, 64);
    }
    float mean = r0 * (1.0f / Hdim);
    float var  = fmaxf(r1 * (1.0f / Hdim) - mean * mean, 0.0f);
    float rstd = rsqrtf(var + 1e-8f);
    float4 g4 = *(const float4*)(lnG + lane * 4);
    float4 b4 = *(const float4*)(lnB + lane * 4);
    float4 y = {(x.x - mean) * rstd * g4.x + b4.x, (x.y - mean) * rstd * g4.y + b4.y,
                (x.z - mean) * rstd * g4.z + b4.z, (x.w - mean) * rstd * g4.w + b4.w};
    *(float4*)(QX + off) = y;
    ushort4 yb = {f2bf(y.x), f2bf(y.y), f2bf(y.z), f2bf(y.w)};
    *(ushort4*)(QXbf + off) = yb;
}

#define GBM 128
#define GBN 128
#define GBK 32

// ---------------- merged q/k/v GEMM: blockIdx.z selects operand set ----------------
// z=0: Qbf = QXbf@qW^T+qb ; z=1: Kbf = Tbf@kW^T+kb ; z=2: VT = transpose(VINbf@vW^T+vb)
__global__ __launch_bounds__(256)
void gemm_qkv_kernel(const unsigned short* __restrict__ QXbf,
                     const unsigned short* __restrict__ Tbf,
                     const unsigned short* __restrict__ VINbf,
                     const unsigned short* __restrict__ qW,
                     const unsigned short* __restrict__ kW,
                     const unsigned short* __restrict__ vW,
                     const float* __restrict__ qb, const float* __restrict__ kb,
                     const float* __restrict__ vb,
                     unsigned short* __restrict__ Qbf,
                     unsigned short* __restrict__ Kbf,
                     unsigned short* __restrict__ VT) {
    // As(8KB) + Ws(8KB) unioned with Ct(34.8KB transpose buffer, z==2 only)
    __shared__ __align__(16) char smem[128 * 136 * 2];
    __bf16 (*As)[GBK] = (__bf16 (*)[GBK])smem;
    __bf16 (*Ws)[GBK] = (__bf16 (*)[GBK])(smem + 8192);
    __bf16 (*Ct)[136] = (__bf16 (*)[136])smem;
    int z = blockIdx.z;
    const unsigned short* A = (z == 0) ? QXbf : (z == 1) ? Tbf : VINbf;
    const unsigned short* W = (z == 0) ? qW : (z == 1) ? kW : vW;
    const float* bias       = (z == 0) ? qb : (z == 1) ? kb : vb;

    int tid = threadIdx.x, lane = tid & 63, w = tid >> 6;
    int wr = w >> 1, wc = w & 1;
    int m0 = blockIdx.y * GBM, n0 = blockIdx.x * GBN;
    f32x4 acc[4][4];
#pragma unroll
    for (int i = 0; i < 4; ++i)
#pragma unroll
        for (int j = 0; j < 4; ++j) acc[i][j] = (f32x4)(0.0f);
    int cA = tid, cB = tid + 256;
    int rA = cA >> 2, kA = (cA & 3) * 8;
    int rB = cB >> 2, kB = (cB & 3) * 8;
    int colq = lane & 15, kq = (lane >> 4) * 8;
    for (int kc = 0; kc < Hdim; kc += GBK) {
        __syncthreads();
        gload16(A + (size_t)(m0 + rA) * Hdim + kc + kA, (__bf16*)As + cA * 8);
        gload16(A + (size_t)(m0 + rB) * Hdim + kc + kB, (__bf16*)As + cB * 8);
        gload16(W + (size_t)(n0 + rA) * Hdim + kc + kA, (__bf16*)Ws + cA * 8);
        gload16(W + (size_t)(n0 + rB) * Hdim + kc + kB, (__bf16*)Ws + cB * 8);
        __syncthreads();
        bf16x8 af[4], bfr[4];
#pragma unroll
        for (int i = 0; i < 4; ++i)
            af[i] = *(const bf16x8*)&As[wr * 64 + i * 16 + colq][kq];
#pragma unroll
        for (int j = 0; j < 4; ++j)
            bfr[j] = *(const bf16x8*)&Ws[wc * 64 + j * 16 + colq][kq];
#pragma unroll
        for (int i = 0; i < 4; ++i)
#pragma unroll
            for (int j = 0; j < 4; ++j)
                acc[i][j] = __builtin_amdgcn_mfma_f32_16x16x32_bf16(af[i], bfr[j], acc[i][j], 0, 0, 0);
    }
    int rowq = (lane >> 4) * 4;
    if (z < 2) {
        unsigned short* outBF = (z == 0) ? Qbf : Kbf;
#pragma unroll
        for (int i = 0; i < 4; ++i)
#pragma unroll
            for (int r = 0; r < 4; ++r) {
                int m = m0 + wr * 64 + i * 16 + rowq + r;
#pragma unroll
                for (int j = 0; j < 4; ++j) {
                    int n = n0 + wc * 64 + j * 16 + colq;
                    outBF[(size_t)m * Hdim + n] = f2bf(acc[i][j][r] + bias[n]);
                }
            }
    } else {
        __syncthreads();   // all frag reads done before Ct overwrites As/Ws
#pragma unroll
        for (int i = 0; i < 4; ++i)
#pragma unroll
            for (int r = 0; r < 4; ++r) {
                int ml = wr * 64 + i * 16 + rowq + r;
#pragma unroll
                for (int j = 0; j < 4; ++j) {
                    int nl = wc * 64 + j * 16 + colq;
                    Ct[nl][ml] = (__bf16)(acc[i][j][r] + bias[n0 + nl]);
                }
            }
        __syncthreads();
        int bb = m0 >> 9, l0 = m0 & 511;
#pragma unroll
        for (int it = 0; it < 8; ++it) {
            int c = tid + it * 256;
            int nl = c >> 4;
            int o8 = (c & 15) * 8;
            int n = n0 + nl;
            int hh = n >> 6, dd = n & 63;
            bf16x8 v = *(const bf16x8*)&Ct[nl][o8];
            *(bf16x8*)(VT + ((((size_t)bb * NHEAD + hh) * HD + dd) * Ldim + l0 + o8)) = v;
        }
    }
}

// ---------------- plain bf16 GEMM 128x128 (c1): C = A@W^T + bias [relu] -> bf16 ----------------
__global__ __launch_bounds__(256)
void gemm_plain_kernel(const unsigned short* __restrict__ A,
                       const unsigned short* __restrict__ W,
                       const float* __restrict__ bias,
                       unsigned short* __restrict__ outBF, int doRelu) {
    __shared__ __bf16 As[GBM][GBK];
    __shared__ __bf16 Ws[GBN][GBK];
    int tid = threadIdx.x, lane = tid & 63, w = tid >> 6;
    int wr = w >> 1, wc = w & 1;
    int m0 = blockIdx.y * GBM, n0 = blockIdx.x * GBN;
    f32x4 acc[4][4];
#pragma unroll
    for (int i = 0; i < 4; ++i)
#pragma unroll
        for (int j = 0; j < 4; ++j) acc[i][j] = (f32x4)(0.0f);
    int cA = tid, cB = tid + 256;
    int rA = cA >> 2, kA = (cA & 3) * 8;
    int rB = cB >> 2, kB = (cB & 3) * 8;
    int colq = lane & 15, kq = (lane >> 4) * 8;
    for (int kc = 0; kc < Hdim; kc += GBK) {
        __syncthreads();
        gload16(A + (size_t)(m0 + rA) * Hdim + kc + kA, (__bf16*)As + cA * 8);
        gload16(A + (size_t)(m0 + rB) * Hdim + kc + kB, (__bf16*)As + cB * 8);
        gload16(W + (size_t)(n0 + rA) * Hdim + kc + kA, (__bf16*)Ws + cA * 8);
        gload16(W + (size_t)(n0 + rB) * Hdim + kc + kB, (__bf16*)Ws + cB * 8);
        __syncthreads();
        bf16x8 af[4], bfr[4];
#pragma unroll
        for (int i = 0; i < 4; ++i)
            af[i] = *(const bf16x8*)&As[wr * 64 + i * 16 + colq][kq];
#pragma unroll
        for (int j = 0; j < 4; ++j)
            bfr[j] = *(const bf16x8*)&Ws[wc * 64 + j * 16 + colq][kq];
#pragma unroll
        for (int i = 0; i < 4; ++i)
#pragma unroll
            for (int j = 0; j < 4; ++j)
                acc[i][j] = __builtin_amdgcn_mfma_f32_16x16x32_bf16(af[i], bfr[j], acc[i][j], 0, 0, 0);
    }
    int rowq = (lane >> 4) * 4;
#pragma unroll
    for (int i = 0; i < 4; ++i)
#pragma unroll
        for (int r = 0; r < 4; ++r) {
            int m = m0 + wr * 64 + i * 16 + rowq + r;
#pragma unroll
            for (int j = 0; j < 4; ++j) {
                int n = n0 + wc * 64 + j * 16 + colq;
                float v = acc[i][j][r] + bias[n];
                if (doRelu) v = fmaxf(v, 0.0f);
                outBF[(size_t)m * Hdim + n] = f2bf(v);
            }
        }
}

// ---------------- c2 GEMM 64x256 + resid + keep + row-LN epilogue ----------------
__global__ __launch_bounds__(256)
void gemm_c2ln_kernel(const unsigned short* __restrict__ A,   // hidden bf16
                      const unsigned short* __restrict__ W,   // c2W bf16
                      const float* __restrict__ bias,
                      float* residQX,
                      const float* __restrict__ keepv,
                      const float* __restrict__ lnG, const float* __restrict__ lnB,
                      const unsigned short* __restrict__ Tbf,  // nullable (for VIN)
                      float* outF,
                      unsigned short* __restrict__ outBF,      // nullable
                      unsigned short* __restrict__ outVIN) {   // nullable
    __shared__ __bf16 As[64][32];
    __shared__ __bf16 Ws[256][32];
    __shared__ float red[4][64][2];
    int tid = threadIdx.x, lane = tid & 63, w = tid >> 6;
    int colq = lane & 15, grp = lane >> 4, rowq = grp * 4, kq = grp * 8;
    int m0 = blockIdx.x * 64;
    f32x4 acc[4][4];
#pragma unroll
    for (int i = 0; i < 4; ++i)
#pragma unroll
        for (int j = 0; j < 4; ++j) acc[i][j] = (f32x4)(0.0f);
    for (int kc = 0; kc < Hdim; kc += 32) {
        __syncthreads();
        gload16(A + (size_t)(m0 + (tid >> 2)) * Hdim + kc + (tid & 3) * 8,
                (__bf16*)As + tid * 8);
#pragma unroll
        for (int it = 0; it < 4; ++it) {
            int c = tid + it * 256;
            gload16(W + (size_t)(c >> 2) * Hdim + kc + (c & 3) * 8, (__bf16*)Ws + c * 8);
        }
        __syncthreads();
        bf16x8 af[4], bfr[4];
#pragma unroll
        for (int i = 0; i < 4; ++i)
            af[i] = *(const bf16x8*)&As[i * 16 + colq][kq];
#pragma unroll
        for (int j = 0; j < 4; ++j)
            bfr[j] = *(const bf16x8*)&Ws[w * 64 + j * 16 + colq][kq];
#pragma unroll
        for (int i = 0; i < 4; ++i)
#pragma unroll
            for (int j = 0; j < 4; ++j)
                acc[i][j] = __builtin_amdgcn_mfma_f32_16x16x32_bf16(af[i], bfr[j], acc[i][j], 0, 0, 0);
    }
#pragma unroll
    for (int i = 0; i < 4; ++i)
#pragma unroll
        for (int r = 0; r < 4; ++r) {
            int m = m0 + i * 16 + rowq + r;
            float kf = keepv[m];
#pragma unroll
            for (int j = 0; j < 4; ++j) {
                int nl = w * 64 + j * 16 + colq;
                float v = acc[i][j][r] + bias[nl] + residQX[(size_t)m * Hdim + nl];
                acc[i][j][r] = v * kf;
            }
        }
#pragma unroll
    for (int i = 0; i < 4; ++i)
#pragma unroll
        for (int r = 0; r < 4; ++r) {
            float s1 = acc[i][0][r] + acc[i][1][r] + acc[i][2][r] + acc[i][3][r];
            float s2 = acc[i][0][r] * acc[i][0][r] + acc[i][1][r] * acc[i][1][r] +
                       acc[i][2][r] * acc[i][2][r] + acc[i][3][r] * acc[i][3][r];
#pragma unroll
            for (int o = 1; o < 16; o <<= 1) {
                s1 += __shfl_xor(s1, o, 64);
                s2 += __shfl_xor(s2, o, 64);
            }
            if (colq == 0) {
                red[w][i * 16 + rowq + r][0] = s1;
                red[w][i * 16 + rowq + r][1] = s2;
            }
        }
    __syncthreads();
    float mean_[4][4], rstd_[4][4];
#pragma unroll
    for (int i = 0; i < 4; ++i)
#pragma unroll
        for (int r = 0; r < 4; ++r) {
            int row = i * 16 + rowq + r;
            float s1 = red[0][row][0] + red[1][row][0] + red[2][row][0] + red[3][row][0];
            float s2 = red[0][row][1] + red[1][row][1] + red[2][row][1] + red[3][row][1];
            float mean = s1 * (1.0f / Hdim);
            float var  = fmaxf(s2 * (1.0f / Hdim) - mean * mean, 0.0f);
            mean_[i][r] = mean;
            rstd_[i][r] = rsqrtf(var + 1e-8f);
        }
#pragma unroll
    for (int i = 0; i < 4; ++i)
#pragma unroll
        for (int r = 0; r < 4; ++r) {
            int m = m0 + i * 16 + rowq + r;
#pragma unroll
            for (int j = 0; j < 4; ++j) {
                int nl = w * 64 + j * 16 + colq;
                float v = acc[i][j][r];
                float y = (v - mean_[i][r]) * rstd_[i][r] * lnG[nl] + lnB[nl];
                outF[(size_t)m * Hdim + nl] = y;
                if (outBF)  outBF[(size_t)m * Hdim + nl]  = f2bf(y);
                if (outVIN) outVIN[(size_t)m * Hdim + nl] =
                    f2bf(v + bf2f(Tbf[(size_t)m * Hdim + nl]));
            }
        }
}

// ---------------- gated causal flash attention v2: 128-row Q tile, no-max exp2 ----------------
// grid: (L/128, NHEAD, B), 256 threads; wave w owns q rows [w*32, w*32+32)
__global__ __launch_bounds__(256)
void attn_mfma_kernel(const unsigned short* __restrict__ Qg,
                      const unsigned short* __restrict__ Kg,
                      const unsigned short* __restrict__ VTg,
                      const float* __restrict__ gates,
                      unsigned short* __restrict__ Ob, int blk) {
    __shared__ __bf16 QPs[128][72];   // Q staging, then P (per-wave 32-row strips)
    __shared__ __bf16 Ks[64][72];
    __shared__ __bf16 VTs[64][72];
    __shared__ float gks[64];
    int qt = blockIdx.x, h = blockIdx.y, b = blockIdx.z;
    int q0 = qt * 128;
    int tid = threadIdx.x, lane = tid & 63, w = tid >> 6;
    int colq = lane & 15, grp = lane >> 4;
    int rowq = grp * 4, kq = grp * 8;
    size_t baseQO = ((size_t)b * Ldim + q0) * Hdim + h * HD;
    // stage Q tile (128 x 64 bf16)
#pragma unroll
    for (int it = 0; it < 4; ++it) {
        int c = tid + it * 256;
        int r = c >> 3, o = (c & 7) * 8;
        *(bf16x8*)&QPs[r][o] = *(const bf16x8*)(Qg + baseQO + (size_t)r * Hdim + o);
    }
    // gq with softmax scale and log2(e) folded in (no-max exp2 softmax)
    float gql[2][4];
#pragma unroll
    for (int i = 0; i < 2; ++i)
#pragma unroll
        for (int r = 0; r < 4; ++r)
            gql[i][r] = gates[((size_t)b * Ldim + q0 + w * 32 + i * 16 + rowq + r) * 2 + blk]
                        * (0.125f * 1.44269504f);
    __syncthreads();
    bf16x8 afq[2][2];
#pragma unroll
    for (int i = 0; i < 2; ++i) {
        afq[i][0] = *(const bf16x8*)&QPs[w * 32 + i * 16 + colq][kq];
        afq[i][1] = *(const bf16x8*)&QPs[w * 32 + i * 16 + colq][32 + kq];
    }
    float lrun[2][4];
    f32x4 accO[2][4];
#pragma unroll
    for (int i = 0; i < 2; ++i)
#pragma unroll
        for (int r = 0; r < 4; ++r) lrun[i][r] = 0.0f;
#pragma unroll
    for (int i = 0; i < 2; ++i)
#pragma unroll
        for (int jd = 0; jd < 4; ++jd) accO[i][jd] = (f32x4)(0.0f);

    int nkt = 2 * qt + 2;
    for (int kt = 0; kt < nkt; ++kt) {
        int k0 = kt * 64;
        __syncthreads();   // prev-iter Ks/VTs/gks readers done; also orders afq reads vs P writes
        {
            size_t baseK = ((size_t)b * Ldim + k0) * Hdim + h * HD;
            size_t baseV = ((size_t)b * NHEAD + h) * HD * Ldim + k0;
            int c0 = tid, c1 = tid + 256;
            int r0 = c0 >> 3, o0 = (c0 & 7) * 8;
            int r1 = c1 >> 3, o1 = (c1 & 7) * 8;
            *(bf16x8*)&Ks[r0][o0]  = *(const bf16x8*)(Kg + baseK + (size_t)r0 * Hdim + o0);
            *(bf16x8*)&Ks[r1][o1]  = *(const bf16x8*)(Kg + baseK + (size_t)r1 * Hdim + o1);
            *(bf16x8*)&VTs[r0][o0] = *(const bf16x8*)(VTg + baseV + (size_t)r0 * Ldim + o0);
            *(bf16x8*)&VTs[r1][o1] = *(const bf16x8*)(VTg + baseV + (size_t)r1 * Ldim + o1);
            if (tid < 64) gks[tid] = gates[((size_t)b * Ldim + k0 + tid) * 2 + blk];
        }
        __syncthreads();

        // S = Q K^T
        f32x4 s[2][4];
#pragma unroll
        for (int i = 0; i < 2; ++i)
#pragma unroll
            for (int j = 0; j < 4; ++j) s[i][j] = (f32x4)(0.0f);
#pragma unroll
        for (int j = 0; j < 4; ++j) {
            bf16x8 bk0 = *(const bf16x8*)&Ks[j * 16 + colq][kq];
            bf16x8 bk1 = *(const bf16x8*)&Ks[j * 16 + colq][32 + kq];
#pragma unroll
            for (int i = 0; i < 2; ++i) {
                s[i][j] = __builtin_amdgcn_mfma_f32_16x16x32_bf16(afq[i][0], bk0, s[i][j], 0, 0, 0);
                s[i][j] = __builtin_amdgcn_mfma_f32_16x16x32_bf16(afq[i][1], bk1, s[i][j], 0, 0, 0);
            }
        }
        float gkv[4];
#pragma unroll
        for (int j = 0; j < 4; ++j) gkv[j] = gks[j * 16 + colq];

        // unshifted exp2 softmax accumulation (scores bounded ~|8| << 88: overflow-safe)
#pragma unroll
        for (int i = 0; i < 2; ++i)
#pragma unroll
            for (int r = 0; r < 4; ++r) {
                int qg = q0 + w * 32 + i * 16 + rowq + r;
                float su = 0.0f;
                float p[4];
#pragma unroll
                for (int j = 0; j < 4; ++j) {
                    int kg = k0 + j * 16 + colq;
                    float v = s[i][j][r] * gql[i][r] * gkv[j];
                    v = (kg > qg) ? -1e38f : v;
                    float e = exp2f(v);
                    p[j] = e;
                    su += e;
                }
#pragma unroll
                for (int off = 1; off < 16; off <<= 1)
                    su += __shfl_xor(su, off, 16);
                lrun[i][r] += su;
#pragma unroll
                for (int j = 0; j < 4; ++j)
                    QPs[w * 32 + i * 16 + rowq + r][j * 16 + colq] = (__bf16)p[j];
            }

        // O += P V (per-wave P strip; within-wave lgkmcnt ordering, no barrier)
#pragma unroll
        for (int i = 0; i < 2; ++i) {
            bf16x8 ap0 = *(const bf16x8*)&QPs[w * 32 + i * 16 + colq][kq];
            bf16x8 ap1 = *(const bf16x8*)&QPs[w * 32 + i * 16 + colq][32 + kq];
#pragma unroll
            for (int jd = 0; jd < 4; ++jd) {
                bf16x8 bv0 = *(const bf16x8*)&VTs[jd * 16 + colq][kq];
                bf16x8 bv1 = *(const bf16x8*)&VTs[jd * 16 + colq][32 + kq];
                accO[i][jd] = __builtin_amdgcn_mfma_f32_16x16x32_bf16(ap0, bv0, accO[i][jd], 0, 0, 0);
                accO[i][jd] = __builtin_amdgcn_mfma_f32_16x16x32_bf16(ap1, bv1, accO[i][jd], 0, 0, 0);
            }
        }
    }
#pragma unroll
    for (int i = 0; i < 2; ++i)
#pragma unroll
        for (int r = 0; r < 4; ++r) {
            float inv = 1.0f / lrun[i][r];
#pragma unroll
            for (int jd = 0; jd < 4; ++jd)
                Ob[baseQO + (size_t)(w * 32 + i * 16 + rowq + r) * Hdim + jd * 16 + colq] =
                    f2bf(accO[i][jd][r] * inv);
        }
}

// ---------------- launcher ----------------
extern "C" void kernel_launch(void* const* d_in, const int* in_sizes, int n_in,
                              void* d_out, int out_size, void* d_ws, size_t ws_size,
                              hipStream_t stream) {
    const int*   seqs_data = (const int*)d_in[0];
    const float* seqs      = (const float*)d_in[1];
    const int*   position  = (const int*)d_in[2];
    const float* time_emb  = (const float*)d_in[3];
    const float* pos_table = (const float*)d_in[4];
    const float* gate_W    = (const float*)d_in[5];
    const float* gate_b    = (const float*)d_in[6];
    const float* ln_attn_g = (const float*)d_in[7];
    const float* ln_attn_b = (const float*)d_in[8];
    const float* qW        = (const float*)d_in[9];
    const float* qb        = (const float*)d_in[10];
    const float* kW        = (const float*)d_in[11];
    const float* kb        = (const float*)d_in[12];
    const float* vW        = (const float*)d_in[13];
    const float* vb        = (const float*)d_in[14];
    const float* ln_ffn_g  = (const float*)d_in[15];
    const float* ln_ffn_b  = (const float*)d_in[16];
    const float* c1W       = (const float*)d_in[17];
    const float* c1b       = (const float*)d_in[18];
    const float* c2W       = (const float*)d_in[19];
    const float* c2b       = (const float*)d_in[20];
    const float* last_g    = (const float*)d_in[21];
    const float* last_b    = (const float*)d_in[22];

    size_t BUF = (size_t)NTOK * Hdim;
    float* fws = (float*)d_ws;
    float* QX    = fws;                       // f32 LN-out / resid
    float* GATES = QX + BUF;                  // NTOK*2
    float* KEEP  = GATES + (size_t)NTOK * 2;  // NTOK
    unsigned short* bws   = (unsigned short*)(KEEP + NTOK);
    unsigned short* Tbf   = bws;
    unsigned short* QXbf  = Tbf + BUF;
    unsigned short* VINbf = QXbf + BUF;       // bf16(S+T) input to v-gemm
    unsigned short* HIDbf = VINbf + BUF;      // ffn hidden
    unsigned short* Qbf   = HIDbf + BUF;
    unsigned short* Kbf   = Qbf + BUF;
    unsigned short* VTbf  = Kbf + BUF;        // V^T [B][NH][HD][L]
    unsigned short* QAbf  = VTbf + BUF;       // attn out bf16
    unsigned short* Wbf   = QAbf + BUF;       // 10 x 65536 bf16 weights
    size_t WB = (size_t)Hdim * Hdim;
    unsigned short* qWbf  = Wbf;
    unsigned short* kWbf  = Wbf + 2 * WB;
    unsigned short* vWbf  = Wbf + 4 * WB;
    unsigned short* c1Wbf = Wbf + 6 * WB;
    unsigned short* c2Wbf = Wbf + 8 * WB;

    castw_kernel<<<dim3(128, 5), 256, 0, stream>>>(qW, kW, vW, c1W, c2W, Wbf);
    prep_ln_kernel<<<NTOK / 4, 256, 0, stream>>>(seqs_data, seqs, position, time_emb,
                                                 pos_table, gate_W, gate_b,
                                                 ln_attn_g, ln_attn_b,
                                                 Tbf, QX, QXbf, VINbf, GATES, KEEP);

    dim3 qkvgrid(Hdim / GBN, NTOK / GBM, 3);   // (2, 256, 3)
    dim3 ggrid(Hdim / GBN, NTOK / GBM);        // (2, 256)
    dim3 agrid(Ldim / 128, NHEAD, Bdim);       // (4, 4, 64)
    for (int i = 0; i < 2; ++i) {
        gemm_qkv_kernel<<<qkvgrid, 256, 0, stream>>>(QXbf, Tbf, VINbf,
                                                     qWbf + i * WB, kWbf + i * WB, vWbf + i * WB,
                                                     qb + i * Hdim, kb + i * Hdim, vb + i * Hdim,
                                                     Qbf, Kbf, VTbf);
        attn_mfma_kernel<<<agrid, 256, 0, stream>>>(Qbf, Kbf, VTbf, GATES, QAbf, i);
        ln2_kernel<<<NTOK / 4, 256, 0, stream>>>(QX, QAbf, QXbf,
                                                 ln_ffn_g + i * Hdim, ln_ffn_b + i * Hdim);
        gemm_plain_kernel<<<ggrid, 256, 0, stream>>>(QXbf, c1Wbf + i * WB, c1b + i * Hdim, HIDbf, 1);
        if (i == 0) {
            gemm_c2ln_kernel<<<NTOK / 64, 256, 0, stream>>>(
                HIDbf, c2Wbf, c2b, QX, KEEP,
                ln_attn_g + Hdim, ln_attn_b + Hdim, Tbf,
                QX, QXbf, VINbf);
        } else {
            gemm_c2ln_kernel<<<NTOK / 64, 256, 0, stream>>>(
                HIDbf, c2Wbf + WB, c2b + Hdim, QX, KEEP,
                last_g, last_b, nullptr,
                (float*)d_out, nullptr, nullptr);
        }
    }
}

// Round 7
// 444.458 us; speedup vs baseline: 4.4352x; 1.0804x over previous
//
#include <hip/hip_runtime.h>
#include <hip/hip_bf16.h>
#include <math.h>

// Problem constants
#define NTOK 32768      // B*L = 64*512
#define Hdim 256
#define Ldim 512
#define Bdim 64
#define NHEAD 4
#define HD 64
#define PADV 49999      // ITEMNUM-1

typedef __bf16 bf16x8 __attribute__((ext_vector_type(8)));
typedef float  f32x4  __attribute__((ext_vector_type(4)));

__device__ __forceinline__ unsigned short f2bf(float f) {
    unsigned int u = __float_as_uint(f);
    unsigned int r = (u + 0x7fffu + ((u >> 16) & 1u)) >> 16;
    return (unsigned short)r;
}
__device__ __forceinline__ float bf2f(unsigned short u) {
    return __uint_as_float(((unsigned int)u) << 16);
}

// async global->LDS, 16B per lane (dest must be wave-uniform base + lane*16)
__device__ __forceinline__ void gload16(const void* g, void* l) {
    __builtin_amdgcn_global_load_lds((const __attribute__((address_space(1))) unsigned int*)g,
                                     (__attribute__((address_space(3))) unsigned int*)l,
                                     16, 0, 0);
}

// ---------------- weight cast: 5 matrices x (2*256*256) f32 -> bf16 ----------------
__global__ __launch_bounds__(256)
void castw_kernel(const float* __restrict__ q, const float* __restrict__ k,
                  const float* __restrict__ v, const float* __restrict__ c1,
                  const float* __restrict__ c2, unsigned short* __restrict__ dst) {
    const float* srcs[5] = {q, k, v, c1, c2};
    const float* s = srcs[blockIdx.y];
    int idx = blockIdx.x * 1024 + threadIdx.x * 4;
    float4 f = *(const float4*)(s + idx);
    unsigned short* d = dst + (size_t)blockIdx.y * 131072 + idx;
    d[0] = f2bf(f.x); d[1] = f2bf(f.y); d[2] = f2bf(f.z); d[3] = f2bf(f.w);
}

// ---------------- prep + ln_attn[0] fused (wave per token) ----------------
__global__ __launch_bounds__(256)
void prep_ln_kernel(const int* __restrict__ seqs_data, const float* __restrict__ seqs,
                    const int* __restrict__ position, const float* __restrict__ time_emb,
                    const float* __restrict__ pos_table, const float* __restrict__ gate_W,
                    const float* __restrict__ gate_b,
                    const float* __restrict__ lnG, const float* __restrict__ lnB,
                    unsigned short* __restrict__ Tbf,
                    float* __restrict__ QX, unsigned short* __restrict__ QXbf,
                    unsigned short* __restrict__ VINbf,
                    float* __restrict__ gates, float* __restrict__ keepv) {
    int tok  = blockIdx.x * 4 + (threadIdx.x >> 6);
    int lane = threadIdx.x & 63;
    size_t off = (size_t)tok * Hdim + lane * 4;
    int pos = position[tok];
    float4 pe = *(const float4*)(pos_table + (size_t)pos * Hdim + lane * 4);
    float4 sq = *(const float4*)(seqs + off);
    float4 tm = *(const float4*)(time_emb + off);
    float keep = (seqs_data[tok] != PADV) ? 1.0f : 0.0f;
    float4 t = {tm.x + pe.x, tm.y + pe.y, tm.z + pe.z, tm.w + pe.w};
    float4 s = {(sq.x + pe.x) * keep, (sq.y + pe.y) * keep,
                (sq.z + pe.z) * keep, (sq.w + pe.w) * keep};
    ushort4 tb = {f2bf(t.x), f2bf(t.y), f2bf(t.z), f2bf(t.w)};
    *(ushort4*)(Tbf + off) = tb;
    float4 gw0 = *(const float4*)(gate_W + lane * 4);
    float4 gw1 = *(const float4*)(gate_W + Hdim + lane * 4);
    float r0 = s.x + s.y + s.z + s.w;
    float r1 = s.x * s.x + s.y * s.y + s.z * s.z + s.w * s.w;
    float r2 = t.x * gw0.x + t.y * gw0.y + t.z * gw0.z + t.w * gw0.w;
    float r3 = t.x * gw1.x + t.y * gw1.y + t.z * gw1.z + t.w * gw1.w;
#pragma unroll
    for (int o = 1; o < 64; o <<= 1) {
        r0 += __shfl_xor(r0, o, 64);
        r1 += __shfl_xor(r1, o, 64);
        r2 += __shfl_xor(r2, o, 64);
        r3 += __shfl_xor(r3, o, 64);
    }
    float mean = r0 * (1.0f / Hdim);
    float var  = fmaxf(r1 * (1.0f / Hdim) - mean * mean, 0.0f);
    float rstd = rsqrtf(var + 1e-8f);
    if (lane == 0) {
        gates[(size_t)tok * 2 + 0] = 1.0f / (1.0f + __expf(-(r2 + gate_b[0])));
        gates[(size_t)tok * 2 + 1] = 1.0f / (1.0f + __expf(-(r3 + gate_b[1])));
        keepv[tok] = keep;
    }
    float4 g4 = *(const float4*)(lnG + lane * 4);
    float4 b4 = *(const float4*)(lnB + lane * 4);
    float4 y = {(s.x - mean) * rstd * g4.x + b4.x, (s.y - mean) * rstd * g4.y + b4.y,
                (s.z - mean) * rstd * g4.z + b4.z, (s.w - mean) * rstd * g4.w + b4.w};
    *(float4*)(QX + off) = y;
    ushort4 yb = {f2bf(y.x), f2bf(y.y), f2bf(y.z), f2bf(y.w)};
    *(ushort4*)(QXbf + off) = yb;
    ushort4 vb = {f2bf(s.x + t.x), f2bf(s.y + t.y), f2bf(s.z + t.z), f2bf(s.w + t.w)};
    *(ushort4*)(VINbf + off) = vb;
}

// ---------------- ln_ffn: x = QX + bf16(QA); LN -> QX, QXbf (wave per token) ----------------
__global__ __launch_bounds__(256)
void ln2_kernel(float* QX, const unsigned short* __restrict__ QA,
                unsigned short* __restrict__ QXbf,
                const float* __restrict__ lnG, const float* __restrict__ lnB) {
    int tok  = blockIdx.x * 4 + (threadIdx.x >> 6);
    int lane = threadIdx.x & 63;
    size_t off = (size_t)tok * Hdim + lane * 4;
    float4 x = *(const float4*)(QX + off);
    ushort4 a = *(const ushort4*)(QA + off);
    x.x += bf2f(a.x); x.y += bf2f(a.y); x.z += bf2f(a.z); x.w += bf2f(a.w);
    float r0 = x.x + x.y + x.z + x.w;
    float r1 = x.x * x.x + x.y * x.y + x.z * x.z + x.w * x.w;
#pragma unroll
    for (int o = 1; o < 64; o <<= 1) {
        r0 += __shfl_xor(r0, o, 64);
        r1 += __shfl_xor(r1, o, 64);
    }
    float mean = r0 * (1.0f / Hdim);
    float var  = fmaxf(r1 * (1.0f / Hdim) - mean * mean, 0.0f);
    float rstd = rsqrtf(var + 1e-8f);
    float4 g4 = *(const float4*)(lnG + lane * 4);
    float4 b4 = *(const float4*)(lnB + lane * 4);
    float4 y = {(x.x - mean) * rstd * g4.x + b4.x, (x.y - mean) * rstd * g4.y + b4.y,
                (x.z - mean) * rstd * g4.z + b4.z, (x.w - mean) * rstd * g4.w + b4.w};
    *(float4*)(QX + off) = y;
    ushort4 yb = {f2bf(y.x), f2bf(y.y), f2bf(y.z), f2bf(y.w)};
    *(ushort4*)(QXbf + off) = yb;
}

#define GBM 128
#define GBN 128
#define GBK 32

// ---------------- merged q/k/v GEMM: blockIdx.z selects operand set ----------------
__global__ __launch_bounds__(256)
void gemm_qkv_kernel(const unsigned short* __restrict__ QXbf,
                     const unsigned short* __restrict__ Tbf,
                     const unsigned short* __restrict__ VINbf,
                     const unsigned short* __restrict__ qW,
                     const unsigned short* __restrict__ kW,
                     const unsigned short* __restrict__ vW,
                     const float* __restrict__ qb, const float* __restrict__ kb,
                     const float* __restrict__ vb,
                     unsigned short* __restrict__ Qbf,
                     unsigned short* __restrict__ Kbf,
                     unsigned short* __restrict__ VT) {
    __shared__ __align__(16) char smem[128 * 136 * 2];
    __bf16 (*As)[GBK] = (__bf16 (*)[GBK])smem;
    __bf16 (*Ws)[GBK] = (__bf16 (*)[GBK])(smem + 8192);
    __bf16 (*Ct)[136] = (__bf16 (*)[136])smem;
    int z = blockIdx.z;
    const unsigned short* A = (z == 0) ? QXbf : (z == 1) ? Tbf : VINbf;
    const unsigned short* W = (z == 0) ? qW : (z == 1) ? kW : vW;
    const float* bias       = (z == 0) ? qb : (z == 1) ? kb : vb;

    int tid = threadIdx.x, lane = tid & 63, w = tid >> 6;
    int wr = w >> 1, wc = w & 1;
    int m0 = blockIdx.y * GBM, n0 = blockIdx.x * GBN;
    f32x4 acc[4][4];
#pragma unroll
    for (int i = 0; i < 4; ++i)
#pragma unroll
        for (int j = 0; j < 4; ++j) acc[i][j] = (f32x4)(0.0f);
    int cA = tid, cB = tid + 256;
    int rA = cA >> 2, kA = (cA & 3) * 8;
    int rB = cB >> 2, kB = (cB & 3) * 8;
    int colq = lane & 15, kq = (lane >> 4) * 8;
    for (int kc = 0; kc < Hdim; kc += GBK) {
        __syncthreads();
        gload16(A + (size_t)(m0 + rA) * Hdim + kc + kA, (__bf16*)As + cA * 8);
        gload16(A + (size_t)(m0 + rB) * Hdim + kc + kB, (__bf16*)As + cB * 8);
        gload16(W + (size_t)(n0 + rA) * Hdim + kc + kA, (__bf16*)Ws + cA * 8);
        gload16(W + (size_t)(n0 + rB) * Hdim + kc + kB, (__bf16*)Ws + cB * 8);
        __syncthreads();
        bf16x8 af[4], bfr[4];
#pragma unroll
        for (int i = 0; i < 4; ++i)
            af[i] = *(const bf16x8*)&As[wr * 64 + i * 16 + colq][kq];
#pragma unroll
        for (int j = 0; j < 4; ++j)
            bfr[j] = *(const bf16x8*)&Ws[wc * 64 + j * 16 + colq][kq];
#pragma unroll
        for (int i = 0; i < 4; ++i)
#pragma unroll
            for (int j = 0; j < 4; ++j)
                acc[i][j] = __builtin_amdgcn_mfma_f32_16x16x32_bf16(af[i], bfr[j], acc[i][j], 0, 0, 0);
    }
    int rowq = (lane >> 4) * 4;
    if (z < 2) {
        unsigned short* outBF = (z == 0) ? Qbf : Kbf;
#pragma unroll
        for (int i = 0; i < 4; ++i)
#pragma unroll
            for (int r = 0; r < 4; ++r) {
                int m = m0 + wr * 64 + i * 16 + rowq + r;
#pragma unroll
                for (int j = 0; j < 4; ++j) {
                    int n = n0 + wc * 64 + j * 16 + colq;
                    outBF[(size_t)m * Hdim + n] = f2bf(acc[i][j][r] + bias[n]);
                }
            }
    } else {
        __syncthreads();
#pragma unroll
        for (int i = 0; i < 4; ++i)
#pragma unroll
            for (int r = 0; r < 4; ++r) {
                int ml = wr * 64 + i * 16 + rowq + r;
#pragma unroll
                for (int j = 0; j < 4; ++j) {
                    int nl = wc * 64 + j * 16 + colq;
                    Ct[nl][ml] = (__bf16)(acc[i][j][r] + bias[n0 + nl]);
                }
            }
        __syncthreads();
        int bb = m0 >> 9, l0 = m0 & 511;
#pragma unroll
        for (int it = 0; it < 8; ++it) {
            int c = tid + it * 256;
            int nl = c >> 4;
            int o8 = (c & 15) * 8;
            int n = n0 + nl;
            int hh = n >> 6, dd = n & 63;
            bf16x8 v = *(const bf16x8*)&Ct[nl][o8];
            *(bf16x8*)(VT + ((((size_t)bb * NHEAD + hh) * HD + dd) * Ldim + l0 + o8)) = v;
        }
    }
}

// ---------------- plain bf16 GEMM 128x128 (c1): C = A@W^T + bias [relu] -> bf16 ----------------
__global__ __launch_bounds__(256)
void gemm_plain_kernel(const unsigned short* __restrict__ A,
                       const unsigned short* __restrict__ W,
                       const float* __restrict__ bias,
                       unsigned short* __restrict__ outBF, int doRelu) {
    __shared__ __bf16 As[GBM][GBK];
    __shared__ __bf16 Ws[GBN][GBK];
    int tid = threadIdx.x, lane = tid & 63, w = tid >> 6;
    int wr = w >> 1, wc = w & 1;
    int m0 = blockIdx.y * GBM, n0 = blockIdx.x * GBN;
    f32x4 acc[4][4];
#pragma unroll
    for (int i = 0; i < 4; ++i)
#pragma unroll
        for (int j = 0; j < 4; ++j) acc[i][j] = (f32x4)(0.0f);
    int cA = tid, cB = tid + 256;
    int rA = cA >> 2, kA = (cA & 3) * 8;
    int rB = cB >> 2, kB = (cB & 3) * 8;
    int colq = lane & 15, kq = (lane >> 4) * 8;
    for (int kc = 0; kc < Hdim; kc += GBK) {
        __syncthreads();
        gload16(A + (size_t)(m0 + rA) * Hdim + kc + kA, (__bf16*)As + cA * 8);
        gload16(A + (size_t)(m0 + rB) * Hdim + kc + kB, (__bf16*)As + cB * 8);
        gload16(W + (size_t)(n0 + rA) * Hdim + kc + kA, (__bf16*)Ws + cA * 8);
        gload16(W + (size_t)(n0 + rB) * Hdim + kc + kB, (__bf16*)Ws + cB * 8);
        __syncthreads();
        bf16x8 af[4], bfr[4];
#pragma unroll
        for (int i = 0; i < 4; ++i)
            af[i] = *(const bf16x8*)&As[wr * 64 + i * 16 + colq][kq];
#pragma unroll
        for (int j = 0; j < 4; ++j)
            bfr[j] = *(const bf16x8*)&Ws[wc * 64 + j * 16 + colq][kq];
#pragma unroll
        for (int i = 0; i < 4; ++i)
#pragma unroll
            for (int j = 0; j < 4; ++j)
                acc[i][j] = __builtin_amdgcn_mfma_f32_16x16x32_bf16(af[i], bfr[j], acc[i][j], 0, 0, 0);
    }
    int rowq = (lane >> 4) * 4;
#pragma unroll
    for (int i = 0; i < 4; ++i)
#pragma unroll
        for (int r = 0; r < 4; ++r) {
            int m = m0 + wr * 64 + i * 16 + rowq + r;
#pragma unroll
            for (int j = 0; j < 4; ++j) {
                int n = n0 + wc * 64 + j * 16 + colq;
                float v = acc[i][j][r] + bias[n];
                if (doRelu) v = fmaxf(v, 0.0f);
                outBF[(size_t)m * Hdim + n] = f2bf(v);
            }
        }
}

// ---------------- c2 GEMM 64x256 + resid + keep + row-LN epilogue ----------------
__global__ __launch_bounds__(256)
void gemm_c2ln_kernel(const unsigned short* __restrict__ A,
                      const unsigned short* __restrict__ W,
                      const float* __restrict__ bias,
                      float* residQX,
                      const float* __restrict__ keepv,
                      const float* __restrict__ lnG, const float* __restrict__ lnB,
                      const unsigned short* __restrict__ Tbf,
                      float* outF,
                      unsigned short* __restrict__ outBF,
                      unsigned short* __restrict__ outVIN) {
    __shared__ __bf16 As[64][32];
    __shared__ __bf16 Ws[256][32];
    __shared__ float red[4][64][2];
    int tid = threadIdx.x, lane = tid & 63, w = tid >> 6;
    int colq = lane & 15, grp = lane >> 4, rowq = grp * 4, kq = grp * 8;
    int m0 = blockIdx.x * 64;
    f32x4 acc[4][4];
#pragma unroll
    for (int i = 0; i < 4; ++i)
#pragma unroll
        for (int j = 0; j < 4; ++j) acc[i][j] = (f32x4)(0.0f);
    for (int kc = 0; kc < Hdim; kc += 32) {
        __syncthreads();
        gload16(A + (size_t)(m0 + (tid >> 2)) * Hdim + kc + (tid & 3) * 8,
                (__bf16*)As + tid * 8);
#pragma unroll
        for (int it = 0; it < 4; ++it) {
            int c = tid + it * 256;
            gload16(W + (size_t)(c >> 2) * Hdim + kc + (c & 3) * 8, (__bf16*)Ws + c * 8);
        }
        __syncthreads();
        bf16x8 af[4], bfr[4];
#pragma unroll
        for (int i = 0; i < 4; ++i)
            af[i] = *(const bf16x8*)&As[i * 16 + colq][kq];
#pragma unroll
        for (int j = 0; j < 4; ++j)
            bfr[j] = *(const bf16x8*)&Ws[w * 64 + j * 16 + colq][kq];
#pragma unroll
        for (int i = 0; i < 4; ++i)
#pragma unroll
            for (int j = 0; j < 4; ++j)
                acc[i][j] = __builtin_amdgcn_mfma_f32_16x16x32_bf16(af[i], bfr[j], acc[i][j], 0, 0, 0);
    }
#pragma unroll
    for (int i = 0; i < 4; ++i)
#pragma unroll
        for (int r = 0; r < 4; ++r) {
            int m = m0 + i * 16 + rowq + r;
            float kf = keepv[m];
#pragma unroll
            for (int j = 0; j < 4; ++j) {
                int nl = w * 64 + j * 16 + colq;
                float v = acc[i][j][r] + bias[nl] + residQX[(size_t)m * Hdim + nl];
                acc[i][j][r] = v * kf;
            }
        }
#pragma unroll
    for (int i = 0; i < 4; ++i)
#pragma unroll
        for (int r = 0; r < 4; ++r) {
            float s1 = acc[i][0][r] + acc[i][1][r] + acc[i][2][r] + acc[i][3][r];
            float s2 = acc[i][0][r] * acc[i][0][r] + acc[i][1][r] * acc[i][1][r] +
                       acc[i][2][r] * acc[i][2][r] + acc[i][3][r] * acc[i][3][r];
#pragma unroll
            for (int o = 1; o < 16; o <<= 1) {
                s1 += __shfl_xor(s1, o, 64);
                s2 += __shfl_xor(s2, o, 64);
            }
            if (colq == 0) {
                red[w][i * 16 + rowq + r][0] = s1;
                red[w][i * 16 + rowq + r][1] = s2;
            }
        }
    __syncthreads();
    float mean_[4][4], rstd_[4][4];
#pragma unroll
    for (int i = 0; i < 4; ++i)
#pragma unroll
        for (int r = 0; r < 4; ++r) {
            int row = i * 16 + rowq + r;
            float s1 = red[0][row][0] + red[1][row][0] + red[2][row][0] + red[3][row][0];
            float s2 = red[0][row][1] + red[1][row][1] + red[2][row][1] + red[3][row][1];
            float mean = s1 * (1.0f / Hdim);
            float var  = fmaxf(s2 * (1.0f / Hdim) - mean * mean, 0.0f);
            mean_[i][r] = mean;
            rstd_[i][r] = rsqrtf(var + 1e-8f);
        }
#pragma unroll
    for (int i = 0; i < 4; ++i)
#pragma unroll
        for (int r = 0; r < 4; ++r) {
            int m = m0 + i * 16 + rowq + r;
#pragma unroll
            for (int j = 0; j < 4; ++j) {
                int nl = w * 64 + j * 16 + colq;
                float v = acc[i][j][r];
                float y = (v - mean_[i][r]) * rstd_[i][r] * lnG[nl] + lnB[nl];
                outF[(size_t)m * Hdim + nl] = y;
                if (outBF)  outBF[(size_t)m * Hdim + nl]  = f2bf(y);
                if (outVIN) outVIN[(size_t)m * Hdim + nl] =
                    f2bf(v + bf2f(Tbf[(size_t)m * Hdim + nl]));
            }
        }
}

// ---------------- persistent per-(b,h) gated causal flash attention ----------------
// grid: 256 blocks (one per (b,h)) x 512 threads (8 waves; wave w owns 16 q-rows/tile)
// LDS: K[512][72] (73728 B) + VT[64][520] (66560 B) + QP[128][72] (18432 B) = 158720 B
#define AK_STRIDE 72
#define AV_STRIDE 520
#define ATTN_LDS (512 * AK_STRIDE * 2 + 64 * AV_STRIDE * 2 + 128 * AK_STRIDE * 2)
__global__ __launch_bounds__(512, 1)
void attn_mfma_kernel(const unsigned short* __restrict__ Qg,
                      const unsigned short* __restrict__ Kg,
                      const unsigned short* __restrict__ VTg,
                      const float* __restrict__ gates,
                      unsigned short* __restrict__ Ob, int blk) {
    extern __shared__ __align__(16) char smem[];
    __bf16 (*Ks)[AK_STRIDE]  = (__bf16 (*)[AK_STRIDE])smem;
    __bf16 (*VTs)[AV_STRIDE] = (__bf16 (*)[AV_STRIDE])(smem + 512 * AK_STRIDE * 2);
    __bf16 (*QPs)[AK_STRIDE] = (__bf16 (*)[AK_STRIDE])(smem + 512 * AK_STRIDE * 2 + 64 * AV_STRIDE * 2);
    int h = blockIdx.x & 3, b = blockIdx.x >> 2;
    int tid = threadIdx.x, lane = tid & 63, w = tid >> 6;
    int colq = lane & 15, grp = lane >> 4;
    int rowq = grp * 4, kq = grp * 8;

    // stage entire K (512x64) and V^T (64x512) for this (b,h)
    size_t baseK = (size_t)b * Ldim * Hdim + h * HD;
#pragma unroll
    for (int it = 0; it < 8; ++it) {
        int c = tid + it * 512;
        int r = c >> 3, o = (c & 7) * 8;
        *(bf16x8*)&Ks[r][o] = *(const bf16x8*)(Kg + baseK + (size_t)r * Hdim + o);
    }
    size_t baseV = ((size_t)b * NHEAD + h) * HD * Ldim;
#pragma unroll
    for (int it = 0; it < 8; ++it) {
        int c = tid + it * 512;
        int d = c >> 6, k = (c & 63) * 8;
        *(bf16x8*)&VTs[d][k] = *(const bf16x8*)(VTg + baseV + (size_t)d * Ldim + k);
    }

    const float lscale = 0.125f * 1.44269504f;
    for (int qt = 0; qt < 4; ++qt) {
        int q0 = qt * 128;
        __syncthreads();   // prev-tile P reads done; (first iter: nothing pending)
        // stage Q tile 128x64
#pragma unroll
        for (int it = 0; it < 2; ++it) {
            int c = tid + it * 512;
            int r = c >> 3, o = (c & 7) * 8;
            *(bf16x8*)&QPs[r][o] =
                *(const bf16x8*)(Qg + (size_t)(b * Ldim + q0 + r) * Hdim + h * HD + o);
        }
        float gql[4];
#pragma unroll
        for (int r = 0; r < 4; ++r)
            gql[r] = gates[((size_t)b * Ldim + q0 + w * 16 + rowq + r) * 2 + blk] * lscale;
        __syncthreads();   // K/VT (first iter) + Q staged
        bf16x8 afq0 = *(const bf16x8*)&QPs[w * 16 + colq][kq];
        bf16x8 afq1 = *(const bf16x8*)&QPs[w * 16 + colq][32 + kq];

        float lrun[4] = {0.0f, 0.0f, 0.0f, 0.0f};
        f32x4 accO[4];
#pragma unroll
        for (int jd = 0; jd < 4; ++jd) accO[jd] = (f32x4)(0.0f);

        int nkt = 2 * qt + 2;
        for (int kt = 0; kt < nkt; ++kt) {
            int k0 = kt * 64;
            // S = Q K^T
            f32x4 s[4];
#pragma unroll
            for (int j = 0; j < 4; ++j) s[j] = (f32x4)(0.0f);
#pragma unroll
            for (int j = 0; j < 4; ++j) {
                bf16x8 bk0 = *(const bf16x8*)&Ks[k0 + j * 16 + colq][kq];
                bf16x8 bk1 = *(const bf16x8*)&Ks[k0 + j * 16 + colq][32 + kq];
                s[j] = __builtin_amdgcn_mfma_f32_16x16x32_bf16(afq0, bk0, s[j], 0, 0, 0);
                s[j] = __builtin_amdgcn_mfma_f32_16x16x32_bf16(afq1, bk1, s[j], 0, 0, 0);
            }
            float gkv[4];
#pragma unroll
            for (int j = 0; j < 4; ++j)
                gkv[j] = gates[((size_t)b * Ldim + k0 + j * 16 + colq) * 2 + blk];

            // unshifted exp2 softmax (scores bounded far below f32 overflow)
#pragma unroll
            for (int r = 0; r < 4; ++r) {
                int qg = q0 + w * 16 + rowq + r;
                float su = 0.0f;
                float p[4];
#pragma unroll
                for (int j = 0; j < 4; ++j) {
                    int kg = k0 + j * 16 + colq;
                    float v = s[j][r] * gql[r] * gkv[j];
                    v = (kg > qg) ? -1e38f : v;
                    float e = exp2f(v);
                    p[j] = e;
                    su += e;
                }
#pragma unroll
                for (int off = 1; off < 16; off <<= 1)
                    su += __shfl_xor(su, off, 16);
                lrun[r] += su;
#pragma unroll
                for (int j = 0; j < 4; ++j)
                    QPs[w * 16 + rowq + r][j * 16 + colq] = (__bf16)p[j];
            }

            // O += P V (own-wave P strip; within-wave lgkmcnt ordering, no barrier)
            bf16x8 ap0 = *(const bf16x8*)&QPs[w * 16 + colq][kq];
            bf16x8 ap1 = *(const bf16x8*)&QPs[w * 16 + colq][32 + kq];
#pragma unroll
            for (int jd = 0; jd < 4; ++jd) {
                bf16x8 bv0 = *(const bf16x8*)&VTs[jd * 16 + colq][k0 + kq];
                bf16x8 bv1 = *(const bf16x8*)&VTs[jd * 16 + colq][k0 + 32 + kq];
                accO[jd] = __builtin_amdgcn_mfma_f32_16x16x32_bf16(ap0, bv0, accO[jd], 0, 0, 0);
                accO[jd] = __builtin_amdgcn_mfma_f32_16x16x32_bf16(ap1, bv1, accO[jd], 0, 0, 0);
            }
        }
        // epilogue for this q-tile
#pragma unroll
        for (int r = 0; r < 4; ++r) {
            float inv = 1.0f / lrun[r];
#pragma unroll
            for (int jd = 0; jd < 4; ++jd)
                Ob[(size_t)(b * Ldim + q0 + w * 16 + rowq + r) * Hdim + h * HD + jd * 16 + colq] =
                    f2bf(accO[jd][r] * inv);
        }
    }
}

// ---------------- launcher ----------------
extern "C" void kernel_launch(void* const* d_in, const int* in_sizes, int n_in,
                              void* d_out, int out_size, void* d_ws, size_t ws_size,
                              hipStream_t stream) {
    const int*   seqs_data = (const int*)d_in[0];
    const float* seqs      = (const float*)d_in[1];
    const int*   position  = (const int*)d_in[2];
    const float* time_emb  = (const float*)d_in[3];
    const float* pos_table = (const float*)d_in[4];
    const float* gate_W    = (const float*)d_in[5];
    const float* gate_b    = (const float*)d_in[6];
    const float* ln_attn_g = (const float*)d_in[7];
    const float* ln_attn_b = (const float*)d_in[8];
    const float* qW        = (const float*)d_in[9];
    const float* qb        = (const float*)d_in[10];
    const float* kW        = (const float*)d_in[11];
    const float* kb        = (const float*)d_in[12];
    const float* vW        = (const float*)d_in[13];
    const float* vb        = (const float*)d_in[14];
    const float* ln_ffn_g  = (const float*)d_in[15];
    const float* ln_ffn_b  = (const float*)d_in[16];
    const float* c1W       = (const float*)d_in[17];
    const float* c1b       = (const float*)d_in[18];
    const float* c2W       = (const float*)d_in[19];
    const float* c2b       = (const float*)d_in[20];
    const float* last_g    = (const float*)d_in[21];
    const float* last_b    = (const float*)d_in[22];

    size_t BUF = (size_t)NTOK * Hdim;
    float* fws = (float*)d_ws;
    float* QX    = fws;
    float* GATES = QX + BUF;
    float* KEEP  = GATES + (size_t)NTOK * 2;
    unsigned short* bws   = (unsigned short*)(KEEP + NTOK);
    unsigned short* Tbf   = bws;
    unsigned short* QXbf  = Tbf + BUF;
    unsigned short* VINbf = QXbf + BUF;
    unsigned short* HIDbf = VINbf + BUF;
    unsigned short* Qbf   = HIDbf + BUF;
    unsigned short* Kbf   = Qbf + BUF;
    unsigned short* VTbf  = Kbf + BUF;
    unsigned short* QAbf  = VTbf + BUF;
    unsigned short* Wbf   = QAbf + BUF;
    size_t WB = (size_t)Hdim * Hdim;
    unsigned short* qWbf  = Wbf;
    unsigned short* kWbf  = Wbf + 2 * WB;
    unsigned short* vWbf  = Wbf + 4 * WB;
    unsigned short* c1Wbf = Wbf + 6 * WB;
    unsigned short* c2Wbf = Wbf + 8 * WB;

    castw_kernel<<<dim3(128, 5), 256, 0, stream>>>(qW, kW, vW, c1W, c2W, Wbf);
    prep_ln_kernel<<<NTOK / 4, 256, 0, stream>>>(seqs_data, seqs, position, time_emb,
                                                 pos_table, gate_W, gate_b,
                                                 ln_attn_g, ln_attn_b,
                                                 Tbf, QX, QXbf, VINbf, GATES, KEEP);

    dim3 qkvgrid(Hdim / GBN, NTOK / GBM, 3);   // (2, 256, 3)
    dim3 ggrid(Hdim / GBN, NTOK / GBM);        // (2, 256)
    for (int i = 0; i < 2; ++i) {
        gemm_qkv_kernel<<<qkvgrid, 256, 0, stream>>>(QXbf, Tbf, VINbf,
                                                     qWbf + i * WB, kWbf + i * WB, vWbf + i * WB,
                                                     qb + i * Hdim, kb + i * Hdim, vb + i * Hdim,
                                                     Qbf, Kbf, VTbf);
        attn_mfma_kernel<<<Bdim * NHEAD, 512, ATTN_LDS, stream>>>(Qbf, Kbf, VTbf, GATES, QAbf, i);
        ln2_kernel<<<NTOK / 4, 256, 0, stream>>>(QX, QAbf, QXbf,
                                                 ln_ffn_g + i * Hdim, ln_ffn_b + i * Hdim);
        gemm_plain_kernel<<<ggrid, 256, 0, stream>>>(QXbf, c1Wbf + i * WB, c1b + i * Hdim, HIDbf, 1);
        if (i == 0) {
            gemm_c2ln_kernel<<<NTOK / 64, 256, 0, stream>>>(
                HIDbf, c2Wbf, c2b, QX, KEEP,
                ln_attn_g + Hdim, ln_attn_b + Hdim, Tbf,
                QX, QXbf, VINbf);
        } else {
            gemm_c2ln_kernel<<<NTOK / 64, 256, 0, stream>>>(
                HIDbf, c2Wbf + WB, c2b + Hdim, QX, KEEP,
                last_g, last_b, nullptr,
                (float*)d_out, nullptr, nullptr);
        }
    }
}